// Round 9
// baseline (3691.053 us; speedup 1.0000x reference)
//
#include <hip/hip_runtime.h>
#include <hip/hip_bf16.h>

#define B_ 2
#define N_ 512
#define DS_ 384
#define DP_ 128
#define H_ 16
#define DH_ 64
#define DI_ 1024
#define MAXSEQ 2048
#define PAD 8

// PROBE ROUND: per-kernel repeat counts (idempotent re-execution for rocprof
// attribution). Revert all to 1 next round.
#define BIAS_REP 10
#define PROJ_REP 64
#define FLASH_REP 64
#define OUT_REP 64

typedef float f32x4 __attribute__((ext_vector_type(4)));
typedef short bf16x8 __attribute__((ext_vector_type(8)));

__device__ __forceinline__ unsigned short f2b(float f) {
    unsigned int u = __builtin_bit_cast(unsigned int, f);
    u += 0x7FFFu + ((u >> 16) & 1u);
    return (unsigned short)(u >> 16);
}
__device__ __forceinline__ float b2f(unsigned short s) {
    unsigned int u = ((unsigned int)s) << 16;
    return __builtin_bit_cast(float, u);
}

// -------- weight transposes + bias-GEMM prep (Gh = gamma*w, Ssum, Tsum) -----
__global__ __launch_bounds__(256) void k_transpose_all(const float* __restrict__ wq,
                                                       const float* __restrict__ wk,
                                                       const float* __restrict__ wv,
                                                       const float* __restrict__ wg,
                                                       const float* __restrict__ wo,
                                                       const float* __restrict__ gamma,
                                                       const float* __restrict__ beta,
                                                       const float* __restrict__ wb,
                                                       unsigned short* __restrict__ Wt,
                                                       unsigned short* __restrict__ Wot,
                                                       unsigned short* __restrict__ GhG,
                                                       float* __restrict__ SsG,
                                                       float* __restrict__ TsG) {
    int z = blockIdx.z;
    if (z == 5) {                       // prep for k_bias (one block only)
        if (blockIdx.x || blockIdx.y) return;
        int t = threadIdx.x;
        for (int idx = t; idx < DP_ * H_; idx += 256) {
            int d = idx >> 4, h = idx & 15;
            GhG[h * DP_ + d] = f2b(gamma[d] * wb[idx]);
        }
        if (t < 32) {
            int h = t & 15;
            const float* src = (t >= 16) ? beta : gamma;
            float s = 0.f;
            for (int d = 0; d < DP_; ++d) s = fmaf(src[d], wb[d * H_ + h], s);
            if (t >= 16) TsG[h] = s; else SsG[h] = s;
        }
        return;
    }
    __shared__ float tile[32][33];
    const float* in;
    unsigned short* out;
    int R, C;
    if (z < 4) {
        in = (z == 0) ? wq : (z == 1) ? wk : (z == 2) ? wv : wg;
        out = Wt + (long)z * 1024 * 384;
        R = 384; C = 1024;
    } else {
        in = wo; out = Wot; R = 1024; C = 384;
    }
    int c0 = blockIdx.x * 32, r0 = blockIdx.y * 32;
    if (c0 >= C || r0 >= R) return;
    int tx = threadIdx.x & 31, ty = threadIdx.x >> 5;
    #pragma unroll
    for (int i = ty; i < 32; i += 8)
        tile[i][tx] = in[(long)(r0 + i) * C + (c0 + tx)];
    __syncthreads();
    #pragma unroll
    for (int i = ty; i < 32; i += 8)
        out[(long)(c0 + i) * R + (r0 + tx)] = f2b(tile[tx][i]);
}

// ---------------- bias: LN(pairwise) @ w_bias + abb -> bf16 [b][h][i][j] ----
__global__ __launch_bounds__(256) void k_bias(const float* __restrict__ pw,
                                              const float* __restrict__ abb,
                                              const unsigned short* __restrict__ GhG,
                                              const float* __restrict__ SsG,
                                              const float* __restrict__ TsG,
                                              unsigned short* __restrict__ biasP) {
    __shared__ float Xs[64 * 128];                          // 32 KB, swizzled rows
    __shared__ float rsum[4][16] __attribute__((aligned(16)));
    __shared__ float rsq[4][16] __attribute__((aligned(16)));
    int t = threadIdx.x;
    int w = t >> 6, lane = t & 63;
    int lane15 = lane & 15, kg = lane >> 4;
    long p0 = (long)blockIdx.x * 64;            // first (b,i,j)-flat row
    int i_blk = (int)((p0 >> 9) & (N_ - 1));
    int j0 = (int)(p0 & (N_ - 1));
    long bb = p0 >> 18;

    // B fragments (heads) from global (4 KB, L2-hot)
    bf16x8 gb[4];
    #pragma unroll
    for (int kk = 0; kk < 4; ++kk)
        gb[kk] = *(const bf16x8*)&GhG[lane15 * DP_ + kk * 32 + kg * 8];
    float sh = SsG[lane15], th = TsG[lane15];

    #pragma unroll 1
    for (int rep = 0; rep < BIAS_REP; ++rep) {
        int zoff = 0;
        asm volatile("" : "+v"(zoff));          // defeat load CSE across reps
        if (rep) __syncthreads();

        const char* src = (const char*)(pw + (p0 << 7)) + zoff;
        char* lds = (char*)Xs;
        #pragma unroll
        for (int c = 0; c < 8; ++c) {
            int L = c * 4096 + t * 16;
            int row = L >> 9, b = L & 511;
            uint4 v = *(const uint4*)(src + L);
            *(uint4*)(lds + (row << 9) + (b ^ ((row & 7) << 4))) = v;
        }
        __syncthreads();

        int row = w * 16 + lane15;
        const char* rbase = lds + (row << 9);
        int sw = (lane15 & 7) << 4;
        f32x4 xa[4], xb4[4];
        #pragma unroll
        for (int kk = 0; kk < 4; ++kk) {
            int b0 = kk * 128 + kg * 32;
            xa[kk]  = *(const f32x4*)(rbase + ((b0) ^ sw));
            xb4[kk] = *(const f32x4*)(rbase + ((b0 + 16) ^ sw));
        }
        float s = 0.f, q = 0.f;
        #pragma unroll
        for (int kk = 0; kk < 4; ++kk) {
            s += xa[kk][0] + xa[kk][1] + xa[kk][2] + xa[kk][3];
            s += xb4[kk][0] + xb4[kk][1] + xb4[kk][2] + xb4[kk][3];
            #pragma unroll
            for (int e = 0; e < 4; ++e) {
                q = fmaf(xa[kk][e], xa[kk][e], q);
                q = fmaf(xb4[kk][e], xb4[kk][e], q);
            }
        }
        s += __shfl_xor(s, 16); s += __shfl_xor(s, 32);
        q += __shfl_xor(q, 16); q += __shfl_xor(q, 32);
        if (lane < 16) { rsum[w][lane15] = s; rsq[w][lane15] = q; }

        f32x4 acc = {};
        #pragma unroll
        for (int kk = 0; kk < 4; ++kk) {
            bf16x8 a;
            unsigned short* ap = (unsigned short*)&a;
            ap[0] = f2b(xa[kk][0]);  ap[1] = f2b(xa[kk][1]);
            ap[2] = f2b(xa[kk][2]);  ap[3] = f2b(xa[kk][3]);
            ap[4] = f2b(xb4[kk][0]); ap[5] = f2b(xb4[kk][1]);
            ap[6] = f2b(xb4[kk][2]); ap[7] = f2b(xb4[kk][3]);
            acc = __builtin_amdgcn_mfma_f32_16x16x32_bf16(a, gb[kk], acc, 0, 0, 0);
        }
        int jr = w * 16 + kg * 4;
        float4 rs = *(const float4*)&rsum[w][kg * 4];
        float4 rq = *(const float4*)&rsq[w][kg * 4];
        float4 av = *(const float4*)(abb + (long)i_blk * MAXSEQ + j0 + jr);
        unsigned short* planeBase = biasP + ((bb * H_ + lane15) * N_ + i_blk) * N_ + j0;
        ushort4 res;
        float mu, var;
        mu = rs.x * (1.f / DP_); var = fmaf(rq.x, 1.f / DP_, -mu * mu);
        res.x = f2b(fmaf(rsqrtf(var + 1e-5f), acc[0] - mu * sh, th + av.x));
        mu = rs.y * (1.f / DP_); var = fmaf(rq.y, 1.f / DP_, -mu * mu);
        res.y = f2b(fmaf(rsqrtf(var + 1e-5f), acc[1] - mu * sh, th + av.y));
        mu = rs.z * (1.f / DP_); var = fmaf(rq.z, 1.f / DP_, -mu * mu);
        res.z = f2b(fmaf(rsqrtf(var + 1e-5f), acc[2] - mu * sh, th + av.z));
        mu = rs.w * (1.f / DP_); var = fmaf(rq.w, 1.f / DP_, -mu * mu);
        res.w = f2b(fmaf(rsqrtf(var + 1e-5f), acc[3] - mu * sh, th + av.w));
        *(ushort4*)(planeBase + jr) = res;
    }
}

// ---------------- QKVG projection GEMM (M=1024, N=4096, K=384) --------------
__global__ __launch_bounds__(256) void k_proj(const float* __restrict__ X,
                                              const unsigned short* __restrict__ Wt,
                                              unsigned short* __restrict__ Qb,
                                              unsigned short* __restrict__ Kb,
                                              unsigned short* __restrict__ Vt,
                                              unsigned short* __restrict__ Xg) {
    __shared__ unsigned short As[128][64 + PAD];
    __shared__ unsigned short Bs[128][64 + PAD];
    int m0 = blockIdx.x * 128;
    int n0 = blockIdx.y * 128;
    int t = threadIdx.x;
    int wave = t >> 6, lane = t & 63;
    int wr = wave >> 1, wc = wave & 1;
    int lane15 = lane & 15, kg = lane >> 4;
    #pragma unroll 1
    for (int rep = 0; rep < PROJ_REP; ++rep) {
        int zoff = 0;
        asm volatile("" : "+v"(zoff));
        f32x4 acc[4][4] = {};
        for (int k0 = 0; k0 < DS_; k0 += 64) {
            __syncthreads();
            {
                int r = t >> 1, half = t & 1;
                const float4* src = (const float4*)(X + (long)(m0 + r) * DS_ + k0 + half * 32 + zoff);
                unsigned short* dst = &As[r][half * 32];
                #pragma unroll
                for (int ii = 0; ii < 8; ++ii) {
                    float4 v = src[ii];
                    dst[ii * 4 + 0] = f2b(v.x); dst[ii * 4 + 1] = f2b(v.y);
                    dst[ii * 4 + 2] = f2b(v.z); dst[ii * 4 + 3] = f2b(v.w);
                }
                const uint4* wsrc = (const uint4*)(Wt + (long)(n0 + r) * DS_ + k0 + half * 32 + zoff);
                uint4* wdst = (uint4*)&Bs[r][half * 32];
                wdst[0] = wsrc[0]; wdst[1] = wsrc[1]; wdst[2] = wsrc[2]; wdst[3] = wsrc[3];
            }
            __syncthreads();
            #pragma unroll
            for (int ks = 0; ks < 2; ++ks) {
                bf16x8 a[4], bb[4];
                #pragma unroll
                for (int mf = 0; mf < 4; ++mf)
                    a[mf] = *(const bf16x8*)&As[wr * 64 + mf * 16 + lane15][ks * 32 + kg * 8];
                #pragma unroll
                for (int nf = 0; nf < 4; ++nf)
                    bb[nf] = *(const bf16x8*)&Bs[wc * 64 + nf * 16 + lane15][ks * 32 + kg * 8];
                #pragma unroll
                for (int mf = 0; mf < 4; ++mf)
                    #pragma unroll
                    for (int nf = 0; nf < 4; ++nf)
                        acc[mf][nf] = __builtin_amdgcn_mfma_f32_16x16x32_bf16(a[mf], bb[nf], acc[mf][nf], 0, 0, 0);
            }
        }
        int p = n0 >> 10;                 // which projection (q,k,v,g)
        int lgrp = lane >> 4;
        #pragma unroll
        for (int mf = 0; mf < 4; ++mf) {
            #pragma unroll
            for (int nf = 0; nf < 4; ++nf) {
                int col = n0 + wc * 64 + nf * 16 + lane15;
                int ch = col & 1023;
                int h = ch >> 6, dh = ch & 63;
                int row0 = m0 + wr * 64 + mf * 16 + lgrp * 4;
                if (p == 0 || p == 1) {
                    unsigned short* base = (p == 0) ? Qb : Kb;
                    float scl = (p == 0) ? 0.125f : 1.0f;
                    #pragma unroll
                    for (int r = 0; r < 4; ++r) {
                        int row = row0 + r;
                        int b = row >> 9, n = row & 511;
                        base[(((long)(b * 16 + h)) * 512 + n) * 64 + dh] = f2b(acc[mf][nf][r] * scl);
                    }
                } else if (p == 2) {
                    int b = row0 >> 9, n = row0 & 511;
                    ushort4 v;
                    v.x = f2b(acc[mf][nf][0]); v.y = f2b(acc[mf][nf][1]);
                    v.z = f2b(acc[mf][nf][2]); v.w = f2b(acc[mf][nf][3]);
                    *(ushort4*)&Vt[(((long)(b * 16 + h)) * 64 + dh) * 512 + n] = v;
                } else {
                    #pragma unroll
                    for (int r = 0; r < 4; ++r) {
                        int row = row0 + r;
                        Xg[(long)row * 1024 + ch] = f2b(acc[mf][nf][r]);
                    }
                }
            }
        }
    }
}

// ---------------- fused flash attention: S=Q@K^T+bias, softmax, P@V, gate ---
__global__ __launch_bounds__(256) void k_flash(const unsigned short* __restrict__ Qb,
                                               const unsigned short* __restrict__ Kb,
                                               const unsigned short* __restrict__ Vt,
                                               const unsigned short* __restrict__ biasP,
                                               const unsigned short* __restrict__ Xg,
                                               unsigned short* __restrict__ Og) {
    __shared__ unsigned short Kt[64][72];    // [j][dh]
    __shared__ unsigned short Vs[64][72];    // [dh][j]
    __shared__ unsigned short Bt[64][72];    // [i][j] bias tile
    __shared__ unsigned short Ps[4][16][72]; // per-wave P [i][j]
    int bh = blockIdx.y;
    int b = bh >> 4, h = bh & 15;
    int i0 = blockIdx.x * 64;
    int t = threadIdx.x, w = t >> 6, lane = t & 63;
    int lane15 = lane & 15, lgrp = lane >> 4;

    bf16x8 qf[2];
    #pragma unroll
    for (int kk = 0; kk < 2; ++kk)
        qf[kk] = *(const bf16x8*)&Qb[((long)bh * 512 + i0 + w * 16 + lane15) * 64 + kk * 32 + lgrp * 8];

    #pragma unroll 1
    for (int rep = 0; rep < FLASH_REP; ++rep) {
        int zoff = 0;
        asm volatile("" : "+v"(zoff));
        float m_run = -1e30f, l_run = 0.f;
        f32x4 o[4] = {};

        for (int jt = 0; jt < 8; ++jt) {
            int j0 = jt * 64;
            __syncthreads();
            #pragma unroll
            for (int i = 0; i < 2; ++i) {
                int f = i * 256 + t;
                int r = f >> 3, c = f & 7;
                *(uint4*)&Kt[r][c * 8] = *(const uint4*)&Kb[((long)bh * 512 + j0 + r) * 64 + c * 8 + zoff];
                *(uint4*)&Vs[r][c * 8] = *(const uint4*)&Vt[((long)bh * 64 + r) * 512 + j0 + c * 8 + zoff];
                *(uint4*)&Bt[r][c * 8] = *(const uint4*)&biasP[(((long)bh * 512) + i0 + r) * 512 + j0 + c * 8 + zoff];
            }
            __syncthreads();

            f32x4 s[4];
            #pragma unroll
            for (int nf = 0; nf < 4; ++nf) {
                f32x4 z = {};
                #pragma unroll
                for (int kk = 0; kk < 2; ++kk) {
                    bf16x8 af = *(const bf16x8*)&Kt[nf * 16 + lane15][kk * 32 + lgrp * 8];
                    z = __builtin_amdgcn_mfma_f32_16x16x32_bf16(af, qf[kk], z, 0, 0, 0);
                }
                s[nf] = z;
            }
            #pragma unroll
            for (int nf = 0; nf < 4; ++nf)
                #pragma unroll
                for (int r = 0; r < 4; ++r)
                    s[nf][r] += b2f(Bt[w * 16 + lane15][nf * 16 + lgrp * 4 + r]);

            float pmax = s[0][0];
            #pragma unroll
            for (int nf = 0; nf < 4; ++nf)
                #pragma unroll
                for (int r = 0; r < 4; ++r) pmax = fmaxf(pmax, s[nf][r]);
            pmax = fmaxf(pmax, __shfl_xor(pmax, 16));
            pmax = fmaxf(pmax, __shfl_xor(pmax, 32));
            float m_new = fmaxf(m_run, pmax);
            float scale = __expf(m_run - m_new);
            float psum = 0.f;
            #pragma unroll
            for (int nf = 0; nf < 4; ++nf)
                #pragma unroll
                for (int r = 0; r < 4; ++r) {
                    s[nf][r] = __expf(s[nf][r] - m_new);
                    psum += s[nf][r];
                }
            psum += __shfl_xor(psum, 16);
            psum += __shfl_xor(psum, 32);
            l_run = l_run * scale + psum;
            m_run = m_new;
            #pragma unroll
            for (int r = 0; r < 4; ++r) {
                float sc = __shfl(scale, lgrp * 4 + r);
                #pragma unroll
                for (int nf = 0; nf < 4; ++nf) o[nf][r] *= sc;
            }
            #pragma unroll
            for (int nf = 0; nf < 4; ++nf)
                #pragma unroll
                for (int r = 0; r < 4; ++r)
                    Ps[w][lane15][nf * 16 + lgrp * 4 + r] = f2b(s[nf][r]);
            #pragma unroll
            for (int kk = 0; kk < 2; ++kk) {
                bf16x8 pa = *(const bf16x8*)&Ps[w][lane15][kk * 32 + lgrp * 8];
                #pragma unroll
                for (int nf = 0; nf < 4; ++nf) {
                    bf16x8 vb = *(const bf16x8*)&Vs[nf * 16 + lane15][kk * 32 + lgrp * 8];
                    o[nf] = __builtin_amdgcn_mfma_f32_16x16x32_bf16(pa, vb, o[nf], 0, 0, 0);
                }
            }
        }
        #pragma unroll
        for (int r = 0; r < 4; ++r) {
            float l_r = __shfl(l_run, lgrp * 4 + r);
            float inv = 1.f / l_r;
            long grow = (long)b * 512 + i0 + w * 16 + lgrp * 4 + r;
            #pragma unroll
            for (int nf = 0; nf < 4; ++nf) {
                int dh = nf * 16 + lane15;
                float xgv = b2f(Xg[grow * 1024 + h * 64 + dh]);
                float gate = 1.f / (1.f + __expf(-xgv));
                Og[grow * 1024 + h * 64 + dh] = f2b(o[nf][r] * inv * gate);
            }
        }
    }
}

// ---------------- output GEMM: out = Og @ w_o (M=1024,N=384,K=1024) ---------
__global__ __launch_bounds__(256) void k_out(const unsigned short* __restrict__ Og,
                                             const unsigned short* __restrict__ Wot,
                                             float* __restrict__ out) {
    __shared__ unsigned short As[128][64 + PAD];
    __shared__ unsigned short Bs[128][64 + PAD];
    int m0 = blockIdx.x * 128, n0 = blockIdx.y * 128;
    int t = threadIdx.x, wave = t >> 6, lane = t & 63;
    int wr = wave >> 1, wc = wave & 1;
    int lane15 = lane & 15, kg = lane >> 4;
    #pragma unroll 1
    for (int rep = 0; rep < OUT_REP; ++rep) {
        int zoff = 0;
        asm volatile("" : "+v"(zoff));
        f32x4 acc[4][4] = {};
        for (int k0 = 0; k0 < 1024; k0 += 64) {
            __syncthreads();
            {
                int r = t >> 1, half = t & 1;
                const uint4* src = (const uint4*)(Og + (long)(m0 + r) * 1024 + k0 + half * 32 + zoff);
                uint4* dst = (uint4*)&As[r][half * 32];
                dst[0] = src[0]; dst[1] = src[1]; dst[2] = src[2]; dst[3] = src[3];
                const uint4* wsrc = (const uint4*)(Wot + (long)(n0 + r) * 1024 + k0 + half * 32 + zoff);
                uint4* wdst = (uint4*)&Bs[r][half * 32];
                wdst[0] = wsrc[0]; wdst[1] = wsrc[1]; wdst[2] = wsrc[2]; wdst[3] = wsrc[3];
            }
            __syncthreads();
            #pragma unroll
            for (int ks = 0; ks < 2; ++ks) {
                bf16x8 a[4], bb[4];
                #pragma unroll
                for (int mf = 0; mf < 4; ++mf)
                    a[mf] = *(const bf16x8*)&As[wr * 64 + mf * 16 + lane15][ks * 32 + kg * 8];
                #pragma unroll
                for (int nf = 0; nf < 4; ++nf)
                    bb[nf] = *(const bf16x8*)&Bs[wc * 64 + nf * 16 + lane15][ks * 32 + kg * 8];
                #pragma unroll
                for (int mf = 0; mf < 4; ++mf)
                    #pragma unroll
                    for (int nf = 0; nf < 4; ++nf)
                        acc[mf][nf] = __builtin_amdgcn_mfma_f32_16x16x32_bf16(a[mf], bb[nf], acc[mf][nf], 0, 0, 0);
            }
        }
        int lgrp = lane >> 4;
        #pragma unroll
        for (int mf = 0; mf < 4; ++mf) {
            #pragma unroll
            for (int nf = 0; nf < 4; ++nf) {
                int col = n0 + wc * 64 + nf * 16 + lane15;
                int row0 = m0 + wr * 64 + mf * 16 + lgrp * 4;
                #pragma unroll
                for (int r = 0; r < 4; ++r)
                    out[(long)(row0 + r) * DS_ + col] = acc[mf][nf][r];
            }
        }
    }
}

extern "C" void kernel_launch(void* const* d_in, const int* in_sizes, int n_in,
                              void* d_out, int out_size, void* d_ws, size_t ws_size,
                              hipStream_t stream) {
    const float* single = (const float*)d_in[0];
    const float* pw     = (const float*)d_in[1];
    const float* gamma  = (const float*)d_in[2];
    const float* beta   = (const float*)d_in[3];
    const float* wb     = (const float*)d_in[4];
    const float* abb    = (const float*)d_in[5];
    const float* wq     = (const float*)d_in[6];
    const float* wk     = (const float*)d_in[7];
    const float* wv     = (const float*)d_in[8];
    const float* wg     = (const float*)d_in[9];
    const float* wo     = (const float*)d_in[10];
    float* out = (float*)d_out;
    char* ws = (char*)d_ws;

    unsigned short* SP  = (unsigned short*)(ws);                 // 16 MB bias [b][h][i][j]
    unsigned short* Qb  = (unsigned short*)(ws + 16777216);      // 2 MB (pre-scaled 0.125)
    unsigned short* Kb  = (unsigned short*)(ws + 18874368);      // 2 MB
    unsigned short* Vt  = (unsigned short*)(ws + 20971520);      // 2 MB [b][h][dh][n]
    unsigned short* Xg  = (unsigned short*)(ws + 23068672);      // 2 MB
    unsigned short* Og  = (unsigned short*)(ws + 25165824);      // 2 MB
    unsigned short* Wt  = (unsigned short*)(ws + 27262976);      // 3 MB [4*1024][384]
    unsigned short* Wot = (unsigned short*)(ws + 30408704);      // 0.75 MB [384][1024]
    unsigned short* GhG = (unsigned short*)(ws + 31195136);      // 4 KB  [16][128] bf16
    float* SsG          = (float*)(ws + 31199232);               // 64 B
    float* TsG          = (float*)(ws + 31199296);               // 64 B

    k_transpose_all<<<dim3(32, 32, 6), 256, 0, stream>>>(wq, wk, wv, wg, wo,
                                                         gamma, beta, wb,
                                                         Wt, Wot, GhG, SsG, TsG);
    k_bias<<<8192, 256, 0, stream>>>(pw, abb, GhG, SsG, TsG, SP);
    k_proj<<<dim3(8, 32), 256, 0, stream>>>(single, Wt, Qb, Kb, Vt, Xg);
    k_flash<<<dim3(8, 32), 256, 0, stream>>>(Qb, Kb, Vt, SP, Xg, Og);
    k_out<<<dim3(8, 3), 256, 0, stream>>>(Og, Wot, out);
}

// Round 10
// 166.680 us; speedup vs baseline: 22.1445x; 22.1445x over previous
//
#include <hip/hip_runtime.h>
#include <hip/hip_bf16.h>

#define B_ 2
#define N_ 512
#define DS_ 384
#define DP_ 128
#define H_ 16
#define DH_ 64
#define DI_ 1024
#define MAXSEQ 2048
#define PAD 8

typedef float f32x4 __attribute__((ext_vector_type(4)));
typedef short bf16x8 __attribute__((ext_vector_type(8)));
typedef const __attribute__((address_space(1))) unsigned int ga_u32;
typedef __attribute__((address_space(3))) unsigned int ld_u32;

__device__ __forceinline__ unsigned short f2b(float f) {
    unsigned int u = __builtin_bit_cast(unsigned int, f);
    u += 0x7FFFu + ((u >> 16) & 1u);
    return (unsigned short)(u >> 16);
}
__device__ __forceinline__ float b2f(unsigned short s) {
    unsigned int u = ((unsigned int)s) << 16;
    return __builtin_bit_cast(float, u);
}

// -------- weight transposes + bias-GEMM prep (Gh = gamma*w, Ssum, Tsum) -----
__global__ __launch_bounds__(256) void k_transpose_all(const float* __restrict__ wq,
                                                       const float* __restrict__ wk,
                                                       const float* __restrict__ wv,
                                                       const float* __restrict__ wg,
                                                       const float* __restrict__ wo,
                                                       const float* __restrict__ gamma,
                                                       const float* __restrict__ beta,
                                                       const float* __restrict__ wb,
                                                       unsigned short* __restrict__ Wt,
                                                       unsigned short* __restrict__ Wot,
                                                       unsigned short* __restrict__ GhG,
                                                       float* __restrict__ SsG,
                                                       float* __restrict__ TsG) {
    int z = blockIdx.z;
    if (z == 5) {                       // prep for k_bias (one block only)
        if (blockIdx.x || blockIdx.y) return;
        int t = threadIdx.x;
        for (int idx = t; idx < DP_ * H_; idx += 256) {
            int d = idx >> 4, h = idx & 15;
            GhG[h * DP_ + d] = f2b(gamma[d] * wb[idx]);
        }
        if (t < 32) {
            int h = t & 15;
            const float* src = (t >= 16) ? beta : gamma;
            float s = 0.f;
            for (int d = 0; d < DP_; ++d) s = fmaf(src[d], wb[d * H_ + h], s);
            if (t >= 16) TsG[h] = s; else SsG[h] = s;
        }
        return;
    }
    __shared__ float tile[32][33];
    const float* in;
    unsigned short* out;
    int R, C;
    if (z < 4) {
        in = (z == 0) ? wq : (z == 1) ? wk : (z == 2) ? wv : wg;
        out = Wt + (long)z * 1024 * 384;
        R = 384; C = 1024;
    } else {
        in = wo; out = Wot; R = 1024; C = 384;
    }
    int c0 = blockIdx.x * 32, r0 = blockIdx.y * 32;
    if (c0 >= C || r0 >= R) return;
    int tx = threadIdx.x & 31, ty = threadIdx.x >> 5;
    #pragma unroll
    for (int i = ty; i < 32; i += 8)
        tile[i][tx] = in[(long)(r0 + i) * C + (c0 + tx)];
    __syncthreads();
    #pragma unroll
    for (int i = ty; i < 32; i += 8)
        out[(long)(c0 + i) * R + (r0 + tx)] = f2b(tile[tx][i]);
}

// ---------------- bias: LN(pairwise) @ w_bias + abb -> bf16 [b][h][i][j] ----
// v6: global_load_lds staging (pre-swizzled SOURCE, linear LDS dest), swizzled
// ds_read_b128 fragments, register stats, MFMA dot. Block = 64 rows.
__global__ __launch_bounds__(256) void k_bias(const float* __restrict__ pw,
                                              const float* __restrict__ abb,
                                              const unsigned short* __restrict__ GhG,
                                              const float* __restrict__ SsG,
                                              const float* __restrict__ TsG,
                                              unsigned short* __restrict__ biasP) {
    __shared__ float Xs[64 * 128];                          // 32 KB
    __shared__ float rsum[4][16] __attribute__((aligned(16)));
    __shared__ float rsq[4][16] __attribute__((aligned(16)));
    int t = threadIdx.x;
    int w = t >> 6, lane = t & 63;
    int lane15 = lane & 15, kg = lane >> 4;
    long p0 = (long)blockIdx.x * 64;            // first (b,i,j)-flat row
    int i_blk = (int)((p0 >> 9) & (N_ - 1));
    int j0 = (int)(p0 & (N_ - 1));
    long bb = p0 >> 18;

    // stage 32 KB: LDS dest linear (wave-uniform base + lane*16), global source
    // pre-swizzled so the swizzled reader below sees the same layout as v5.
    {
        const char* src = (const char*)(pw + (p0 << 7));
        #pragma unroll
        for (int c = 0; c < 8; ++c) {
            int L = (w * 8 + c) * 1024 + lane * 16;   // linear LDS byte offset
            int row = L >> 9, bp = L & 511;
            const char* gaddr = src + ((row << 9) | (bp ^ ((row & 7) << 4)));
            __builtin_amdgcn_global_load_lds((ga_u32*)gaddr,
                                             (ld_u32*)((char*)Xs + (w * 8 + c) * 1024),
                                             16, 0, 0);
        }
    }

    // B fragments (heads) from global (4 KB, L2-hot) — independent of staging
    bf16x8 gb[4];
    #pragma unroll
    for (int kk = 0; kk < 4; ++kk)
        gb[kk] = *(const bf16x8*)&GhG[lane15 * DP_ + kk * 32 + kg * 8];
    float sh = SsG[lane15], th = TsG[lane15];
    __syncthreads();                    // drains vmcnt (global_load_lds) too

    // fragments: row = w*16 + lane15, k-chunk kk, floats kg*8..+8 (swizzled read)
    int row = w * 16 + lane15;
    const char* rbase = (const char*)Xs + (row << 9);
    int sw = (lane15 & 7) << 4;
    f32x4 xa[4], xb4[4];
    #pragma unroll
    for (int kk = 0; kk < 4; ++kk) {
        int b0 = kk * 128 + kg * 32;
        xa[kk]  = *(const f32x4*)(rbase + ((b0) ^ sw));
        xb4[kk] = *(const f32x4*)(rbase + ((b0 + 16) ^ sw));
    }
    // local stats over this lane's 32 elems (exact fp32)
    float s = 0.f, q = 0.f;
    #pragma unroll
    for (int kk = 0; kk < 4; ++kk) {
        s += xa[kk][0] + xa[kk][1] + xa[kk][2] + xa[kk][3];
        s += xb4[kk][0] + xb4[kk][1] + xb4[kk][2] + xb4[kk][3];
        #pragma unroll
        for (int e = 0; e < 4; ++e) {
            q = fmaf(xa[kk][e], xa[kk][e], q);
            q = fmaf(xb4[kk][e], xb4[kk][e], q);
        }
    }
    s += __shfl_xor(s, 16); s += __shfl_xor(s, 32);
    q += __shfl_xor(q, 16); q += __shfl_xor(q, 32);
    if (lane < 16) { rsum[w][lane15] = s; rsq[w][lane15] = q; }

    // convert fragments and MFMA
    f32x4 acc = {};
    #pragma unroll
    for (int kk = 0; kk < 4; ++kk) {
        bf16x8 a;
        unsigned short* ap = (unsigned short*)&a;
        ap[0] = f2b(xa[kk][0]);  ap[1] = f2b(xa[kk][1]);
        ap[2] = f2b(xa[kk][2]);  ap[3] = f2b(xa[kk][3]);
        ap[4] = f2b(xb4[kk][0]); ap[5] = f2b(xb4[kk][1]);
        ap[6] = f2b(xb4[kk][2]); ap[7] = f2b(xb4[kk][3]);
        acc = __builtin_amdgcn_mfma_f32_16x16x32_bf16(a, gb[kk], acc, 0, 0, 0);
    }
    // epilogue: lane holds col h=lane15, rows w*16 + kg*4 + r
    int jr = w * 16 + kg * 4;
    float4 rs = *(const float4*)&rsum[w][kg * 4];
    float4 rq = *(const float4*)&rsq[w][kg * 4];
    float4 av = *(const float4*)(abb + (long)i_blk * MAXSEQ + j0 + jr);
    unsigned short* planeBase = biasP + ((bb * H_ + lane15) * N_ + i_blk) * N_ + j0;
    ushort4 res;
    float mu, var;
    mu = rs.x * (1.f / DP_); var = fmaf(rq.x, 1.f / DP_, -mu * mu);
    res.x = f2b(fmaf(rsqrtf(var + 1e-5f), acc[0] - mu * sh, th + av.x));
    mu = rs.y * (1.f / DP_); var = fmaf(rq.y, 1.f / DP_, -mu * mu);
    res.y = f2b(fmaf(rsqrtf(var + 1e-5f), acc[1] - mu * sh, th + av.y));
    mu = rs.z * (1.f / DP_); var = fmaf(rq.z, 1.f / DP_, -mu * mu);
    res.z = f2b(fmaf(rsqrtf(var + 1e-5f), acc[2] - mu * sh, th + av.z));
    mu = rs.w * (1.f / DP_); var = fmaf(rq.w, 1.f / DP_, -mu * mu);
    res.w = f2b(fmaf(rsqrtf(var + 1e-5f), acc[3] - mu * sh, th + av.w));
    *(ushort4*)(planeBase + jr) = res;
}

// ---------------- QKVG projection GEMM (M=1024, N=4096, K=384) --------------
// v2: register-prefetch next K-tile (T14) — hides HBM latency under MFMA.
__global__ __launch_bounds__(256) void k_proj(const float* __restrict__ X,
                                              const unsigned short* __restrict__ Wt,
                                              unsigned short* __restrict__ Qb,
                                              unsigned short* __restrict__ Kb,
                                              unsigned short* __restrict__ Vt,
                                              unsigned short* __restrict__ Xg) {
    __shared__ unsigned short As[128][64 + PAD];
    __shared__ unsigned short Bs[128][64 + PAD];
    int m0 = blockIdx.x * 128;
    int n0 = blockIdx.y * 128;
    int t = threadIdx.x;
    int wave = t >> 6, lane = t & 63;
    int wr = wave >> 1, wc = wave & 1;
    int lane15 = lane & 15, kg = lane >> 4;
    int r = t >> 1, half = t & 1;
    f32x4 acc[4][4] = {};
    float4 xr[8];
    uint4 wreg[4];
    {
        const float4* src = (const float4*)(X + (long)(m0 + r) * DS_ + half * 32);
        #pragma unroll
        for (int ii = 0; ii < 8; ++ii) xr[ii] = src[ii];
        const uint4* wsrc = (const uint4*)(Wt + (long)(n0 + r) * DS_ + half * 32);
        #pragma unroll
        for (int ii = 0; ii < 4; ++ii) wreg[ii] = wsrc[ii];
    }
    for (int k0 = 0; k0 < DS_; k0 += 64) {
        __syncthreads();
        {
            unsigned short* dst = &As[r][half * 32];
            #pragma unroll
            for (int ii = 0; ii < 8; ++ii) {
                dst[ii * 4 + 0] = f2b(xr[ii].x); dst[ii * 4 + 1] = f2b(xr[ii].y);
                dst[ii * 4 + 2] = f2b(xr[ii].z); dst[ii * 4 + 3] = f2b(xr[ii].w);
            }
            uint4* wdst = (uint4*)&Bs[r][half * 32];
            wdst[0] = wreg[0]; wdst[1] = wreg[1]; wdst[2] = wreg[2]; wdst[3] = wreg[3];
        }
        __syncthreads();
        if (k0 + 64 < DS_) {            // prefetch next tile during compute
            const float4* src = (const float4*)(X + (long)(m0 + r) * DS_ + k0 + 64 + half * 32);
            #pragma unroll
            for (int ii = 0; ii < 8; ++ii) xr[ii] = src[ii];
            const uint4* wsrc = (const uint4*)(Wt + (long)(n0 + r) * DS_ + k0 + 64 + half * 32);
            #pragma unroll
            for (int ii = 0; ii < 4; ++ii) wreg[ii] = wsrc[ii];
        }
        #pragma unroll
        for (int ks = 0; ks < 2; ++ks) {
            bf16x8 a[4], bb[4];
            #pragma unroll
            for (int mf = 0; mf < 4; ++mf)
                a[mf] = *(const bf16x8*)&As[wr * 64 + mf * 16 + lane15][ks * 32 + kg * 8];
            #pragma unroll
            for (int nf = 0; nf < 4; ++nf)
                bb[nf] = *(const bf16x8*)&Bs[wc * 64 + nf * 16 + lane15][ks * 32 + kg * 8];
            #pragma unroll
            for (int mf = 0; mf < 4; ++mf)
                #pragma unroll
                for (int nf = 0; nf < 4; ++nf)
                    acc[mf][nf] = __builtin_amdgcn_mfma_f32_16x16x32_bf16(a[mf], bb[nf], acc[mf][nf], 0, 0, 0);
        }
    }
    int p = n0 >> 10;                 // which projection (q,k,v,g)
    int lgrp = lane >> 4;
    #pragma unroll
    for (int mf = 0; mf < 4; ++mf) {
        #pragma unroll
        for (int nf = 0; nf < 4; ++nf) {
            int col = n0 + wc * 64 + nf * 16 + lane15;
            int ch = col & 1023;
            int h = ch >> 6, dh = ch & 63;
            int row0 = m0 + wr * 64 + mf * 16 + lgrp * 4;
            if (p == 0 || p == 1) {
                unsigned short* base = (p == 0) ? Qb : Kb;
                float scl = (p == 0) ? 0.125f : 1.0f;
                #pragma unroll
                for (int rr = 0; rr < 4; ++rr) {
                    int rowx = row0 + rr;
                    int b = rowx >> 9, n = rowx & 511;
                    base[(((long)(b * 16 + h)) * 512 + n) * 64 + dh] = f2b(acc[mf][nf][rr] * scl);
                }
            } else if (p == 2) {
                int b = row0 >> 9, n = row0 & 511;
                ushort4 v;
                v.x = f2b(acc[mf][nf][0]); v.y = f2b(acc[mf][nf][1]);
                v.z = f2b(acc[mf][nf][2]); v.w = f2b(acc[mf][nf][3]);
                *(ushort4*)&Vt[(((long)(b * 16 + h)) * 64 + dh) * 512 + n] = v;
            } else {
                #pragma unroll
                for (int rr = 0; rr < 4; ++rr) {
                    int rowx = row0 + rr;
                    Xg[(long)rowx * 1024 + ch] = f2b(acc[mf][nf][rr]);
                }
            }
        }
    }
}

// ---------------- fused flash attention: S=Q@K^T+bias, softmax, P@V, gate ---
// v2: register-prefetch next K/V/B tile (T14); vectorized Bt reads + Ps writes.
__global__ __launch_bounds__(256) void k_flash(const unsigned short* __restrict__ Qb,
                                               const unsigned short* __restrict__ Kb,
                                               const unsigned short* __restrict__ Vt,
                                               const unsigned short* __restrict__ biasP,
                                               const unsigned short* __restrict__ Xg,
                                               unsigned short* __restrict__ Og) {
    __shared__ unsigned short Kt[64][72];    // [j][dh]
    __shared__ unsigned short Vs[64][72];    // [dh][j]
    __shared__ unsigned short Bt[64][72];    // [i][j] bias tile
    __shared__ unsigned short Ps[4][16][72]; // per-wave P [i][j]
    int bh = blockIdx.y;
    int b = bh >> 4, h = bh & 15;
    int i0 = blockIdx.x * 64;
    int t = threadIdx.x, w = t >> 6, lane = t & 63;
    int lane15 = lane & 15, lgrp = lane >> 4;
    int r0_ = t >> 3, c0_ = t & 7;
    int r1_ = (256 + t) >> 3, c1_ = t & 7;

    bf16x8 qf[2];
    #pragma unroll
    for (int kk = 0; kk < 2; ++kk)
        qf[kk] = *(const bf16x8*)&Qb[((long)bh * 512 + i0 + w * 16 + lane15) * 64 + kk * 32 + lgrp * 8];

    float m_run = -1e30f, l_run = 0.f;
    f32x4 o[4] = {};   // o[nf][r] = O[i0+w*16+lgrp*4+r][nf*16+lane15]

    uint4 rk[2], rv[2], rb[2];
#define FL_LOAD(JT) do { int jq = (JT) * 64; \
    rk[0] = *(const uint4*)&Kb[((long)bh * 512 + jq + r0_) * 64 + c0_ * 8]; \
    rv[0] = *(const uint4*)&Vt[((long)bh * 64 + r0_) * 512 + jq + c0_ * 8]; \
    rb[0] = *(const uint4*)&biasP[(((long)bh * 512) + i0 + r0_) * 512 + jq + c0_ * 8]; \
    rk[1] = *(const uint4*)&Kb[((long)bh * 512 + jq + r1_) * 64 + c1_ * 8]; \
    rv[1] = *(const uint4*)&Vt[((long)bh * 64 + r1_) * 512 + jq + c1_ * 8]; \
    rb[1] = *(const uint4*)&biasP[(((long)bh * 512) + i0 + r1_) * 512 + jq + c1_ * 8]; } while (0)

    FL_LOAD(0);
    for (int jt = 0; jt < 8; ++jt) {
        __syncthreads();   // previous tile fully consumed
        *(uint4*)&Kt[r0_][c0_ * 8] = rk[0];
        *(uint4*)&Vs[r0_][c0_ * 8] = rv[0];
        *(uint4*)&Bt[r0_][c0_ * 8] = rb[0];
        *(uint4*)&Kt[r1_][c1_ * 8] = rk[1];
        *(uint4*)&Vs[r1_][c1_ * 8] = rv[1];
        *(uint4*)&Bt[r1_][c1_ * 8] = rb[1];
        __syncthreads();
        if (jt < 7) FL_LOAD(jt + 1);    // issue next loads; hide under compute

        // S^T[j][i]: A = K[j][dh], B = Q[i][dh]
        f32x4 s[4];
        #pragma unroll
        for (int nf = 0; nf < 4; ++nf) {
            f32x4 z = {};
            #pragma unroll
            for (int kk = 0; kk < 2; ++kk) {
                bf16x8 af = *(const bf16x8*)&Kt[nf * 16 + lane15][kk * 32 + lgrp * 8];
                z = __builtin_amdgcn_mfma_f32_16x16x32_bf16(af, qf[kk], z, 0, 0, 0);
            }
            s[nf] = z;
        }
        // bias add (vector b64 reads)
        #pragma unroll
        for (int nf = 0; nf < 4; ++nf) {
            ushort4 bv = *(const ushort4*)&Bt[w * 16 + lane15][nf * 16 + lgrp * 4];
            s[nf][0] += b2f(bv.x); s[nf][1] += b2f(bv.y);
            s[nf][2] += b2f(bv.z); s[nf][3] += b2f(bv.w);
        }

        // online softmax, lane owns row i = lane15 within wave
        float pmax = s[0][0];
        #pragma unroll
        for (int nf = 0; nf < 4; ++nf)
            #pragma unroll
            for (int rr = 0; rr < 4; ++rr) pmax = fmaxf(pmax, s[nf][rr]);
        pmax = fmaxf(pmax, __shfl_xor(pmax, 16));
        pmax = fmaxf(pmax, __shfl_xor(pmax, 32));
        float m_new = fmaxf(m_run, pmax);
        float scale = __expf(m_run - m_new);
        float psum = 0.f;
        #pragma unroll
        for (int nf = 0; nf < 4; ++nf)
            #pragma unroll
            for (int rr = 0; rr < 4; ++rr) {
                s[nf][rr] = __expf(s[nf][rr] - m_new);
                psum += s[nf][rr];
            }
        psum += __shfl_xor(psum, 16);
        psum += __shfl_xor(psum, 32);
        l_run = l_run * scale + psum;
        m_run = m_new;
        #pragma unroll
        for (int rr = 0; rr < 4; ++rr) {
            float sc = __shfl(scale, lgrp * 4 + rr);
            #pragma unroll
            for (int nf = 0; nf < 4; ++nf) o[nf][rr] *= sc;
        }
        // P -> LDS (vector b64 writes)
        #pragma unroll
        for (int nf = 0; nf < 4; ++nf) {
            ushort4 pv_;
            pv_.x = f2b(s[nf][0]); pv_.y = f2b(s[nf][1]);
            pv_.z = f2b(s[nf][2]); pv_.w = f2b(s[nf][3]);
            *(ushort4*)&Ps[w][lane15][nf * 16 + lgrp * 4] = pv_;
        }
        // PV: A = P[i][j], B = V[dh][j]
        #pragma unroll
        for (int kk = 0; kk < 2; ++kk) {
            bf16x8 pa = *(const bf16x8*)&Ps[w][lane15][kk * 32 + lgrp * 8];
            #pragma unroll
            for (int nf = 0; nf < 4; ++nf) {
                bf16x8 vb = *(const bf16x8*)&Vs[nf * 16 + lane15][kk * 32 + lgrp * 8];
                o[nf] = __builtin_amdgcn_mfma_f32_16x16x32_bf16(pa, vb, o[nf], 0, 0, 0);
            }
        }
    }
#undef FL_LOAD
    // epilogue: divide by l, sigmoid gate, store
    #pragma unroll
    for (int rr = 0; rr < 4; ++rr) {
        float l_r = __shfl(l_run, lgrp * 4 + rr);
        float inv = 1.f / l_r;
        long grow = (long)b * 512 + i0 + w * 16 + lgrp * 4 + rr;
        #pragma unroll
        for (int nf = 0; nf < 4; ++nf) {
            int dh = nf * 16 + lane15;
            float xgv = b2f(Xg[grow * 1024 + h * 64 + dh]);
            float gate = 1.f / (1.f + __expf(-xgv));
            Og[grow * 1024 + h * 64 + dh] = f2b(o[nf][rr] * inv * gate);
        }
    }
}

// ---------------- output GEMM: out = Og @ w_o (M=1024,N=384,K=1024) ---------
// v2: register-prefetch next K-tile (24 blocks, latency was fully exposed).
__global__ __launch_bounds__(256) void k_out(const unsigned short* __restrict__ Og,
                                             const unsigned short* __restrict__ Wot,
                                             float* __restrict__ out) {
    __shared__ unsigned short As[128][64 + PAD];
    __shared__ unsigned short Bs[128][64 + PAD];
    int m0 = blockIdx.x * 128, n0 = blockIdx.y * 128;
    int t = threadIdx.x, wave = t >> 6, lane = t & 63;
    int wr = wave >> 1, wc = wave & 1;
    int lane15 = lane & 15, kg = lane >> 4;
    int r = t >> 1, half = t & 1;
    f32x4 acc[4][4] = {};
    uint4 ar[4], br[4];
    {
        const uint4* src = (const uint4*)(Og + (long)(m0 + r) * 1024 + half * 32);
        const uint4* wsrc = (const uint4*)(Wot + (long)(n0 + r) * 1024 + half * 32);
        #pragma unroll
        for (int ii = 0; ii < 4; ++ii) { ar[ii] = src[ii]; br[ii] = wsrc[ii]; }
    }
    for (int k0 = 0; k0 < 1024; k0 += 64) {
        __syncthreads();
        {
            uint4* dst = (uint4*)&As[r][half * 32];
            uint4* wdst = (uint4*)&Bs[r][half * 32];
            #pragma unroll
            for (int ii = 0; ii < 4; ++ii) { dst[ii] = ar[ii]; wdst[ii] = br[ii]; }
        }
        __syncthreads();
        if (k0 + 64 < 1024) {
            const uint4* src = (const uint4*)(Og + (long)(m0 + r) * 1024 + k0 + 64 + half * 32);
            const uint4* wsrc = (const uint4*)(Wot + (long)(n0 + r) * 1024 + k0 + 64 + half * 32);
            #pragma unroll
            for (int ii = 0; ii < 4; ++ii) { ar[ii] = src[ii]; br[ii] = wsrc[ii]; }
        }
        #pragma unroll
        for (int ks = 0; ks < 2; ++ks) {
            bf16x8 a[4], bb[4];
            #pragma unroll
            for (int mf = 0; mf < 4; ++mf)
                a[mf] = *(const bf16x8*)&As[wr * 64 + mf * 16 + lane15][ks * 32 + kg * 8];
            #pragma unroll
            for (int nf = 0; nf < 4; ++nf)
                bb[nf] = *(const bf16x8*)&Bs[wc * 64 + nf * 16 + lane15][ks * 32 + kg * 8];
            #pragma unroll
            for (int mf = 0; mf < 4; ++mf)
                #pragma unroll
                for (int nf = 0; nf < 4; ++nf)
                    acc[mf][nf] = __builtin_amdgcn_mfma_f32_16x16x32_bf16(a[mf], bb[nf], acc[mf][nf], 0, 0, 0);
        }
    }
    int lgrp = lane >> 4;
    #pragma unroll
    for (int mf = 0; mf < 4; ++mf) {
        #pragma unroll
        for (int nf = 0; nf < 4; ++nf) {
            int col = n0 + wc * 64 + nf * 16 + lane15;
            int row0 = m0 + wr * 64 + mf * 16 + lgrp * 4;
            #pragma unroll
            for (int rr = 0; rr < 4; ++rr)
                out[(long)(row0 + rr) * DS_ + col] = acc[mf][nf][rr];
        }
    }
}

extern "C" void kernel_launch(void* const* d_in, const int* in_sizes, int n_in,
                              void* d_out, int out_size, void* d_ws, size_t ws_size,
                              hipStream_t stream) {
    const float* single = (const float*)d_in[0];
    const float* pw     = (const float*)d_in[1];
    const float* gamma  = (const float*)d_in[2];
    const float* beta   = (const float*)d_in[3];
    const float* wb     = (const float*)d_in[4];
    const float* abb    = (const float*)d_in[5];
    const float* wq     = (const float*)d_in[6];
    const float* wk     = (const float*)d_in[7];
    const float* wv     = (const float*)d_in[8];
    const float* wg     = (const float*)d_in[9];
    const float* wo     = (const float*)d_in[10];
    float* out = (float*)d_out;
    char* ws = (char*)d_ws;

    unsigned short* SP  = (unsigned short*)(ws);                 // 16 MB bias [b][h][i][j]
    unsigned short* Qb  = (unsigned short*)(ws + 16777216);      // 2 MB (pre-scaled 0.125)
    unsigned short* Kb  = (unsigned short*)(ws + 18874368);      // 2 MB
    unsigned short* Vt  = (unsigned short*)(ws + 20971520);      // 2 MB [b][h][dh][n]
    unsigned short* Xg  = (unsigned short*)(ws + 23068672);      // 2 MB
    unsigned short* Og  = (unsigned short*)(ws + 25165824);      // 2 MB
    unsigned short* Wt  = (unsigned short*)(ws + 27262976);      // 3 MB [4*1024][384]
    unsigned short* Wot = (unsigned short*)(ws + 30408704);      // 0.75 MB [384][1024]
    unsigned short* GhG = (unsigned short*)(ws + 31195136);      // 4 KB  [16][128] bf16
    float* SsG          = (float*)(ws + 31199232);               // 64 B
    float* TsG          = (float*)(ws + 31199296);               // 64 B

    k_transpose_all<<<dim3(32, 32, 6), 256, 0, stream>>>(wq, wk, wv, wg, wo,
                                                         gamma, beta, wb,
                                                         Wt, Wot, GhG, SsG, TsG);
    k_bias<<<8192, 256, 0, stream>>>(pw, abb, GhG, SsG, TsG, SP);
    k_proj<<<dim3(8, 32), 256, 0, stream>>>(single, Wt, Qb, Kb, Vt, Xg);
    k_flash<<<dim3(8, 32), 256, 0, stream>>>(Qb, Kb, Vt, SP, Xg, Og);
    k_out<<<dim3(8, 3), 256, 0, stream>>>(Og, Wot, out);
}

// Round 11
// 165.815 us; speedup vs baseline: 22.2601x; 1.0052x over previous
//
#include <hip/hip_runtime.h>
#include <hip/hip_bf16.h>

#define B_ 2
#define N_ 512
#define DS_ 384
#define DP_ 128
#define H_ 16
#define DH_ 64
#define DI_ 1024
#define MAXSEQ 2048
#define PAD 8

typedef float f32x4 __attribute__((ext_vector_type(4)));
typedef short bf16x8 __attribute__((ext_vector_type(8)));

__device__ __forceinline__ unsigned short f2b(float f) {
    unsigned int u = __builtin_bit_cast(unsigned int, f);
    u += 0x7FFFu + ((u >> 16) & 1u);
    return (unsigned short)(u >> 16);
}
__device__ __forceinline__ float b2f(unsigned short s) {
    unsigned int u = ((unsigned int)s) << 16;
    return __builtin_bit_cast(float, u);
}

// -------- weight transposes + bias-GEMM prep (Gh = gamma*w, Ssum, Tsum) -----
__global__ __launch_bounds__(256) void k_transpose_all(const float* __restrict__ wq,
                                                       const float* __restrict__ wk,
                                                       const float* __restrict__ wv,
                                                       const float* __restrict__ wg,
                                                       const float* __restrict__ wo,
                                                       const float* __restrict__ gamma,
                                                       const float* __restrict__ beta,
                                                       const float* __restrict__ wb,
                                                       unsigned short* __restrict__ Wt,
                                                       unsigned short* __restrict__ Wot,
                                                       unsigned short* __restrict__ GhG,
                                                       float* __restrict__ SsG,
                                                       float* __restrict__ TsG) {
    int z = blockIdx.z;
    if (z == 5) {                       // prep for k_bias (one block only)
        if (blockIdx.x || blockIdx.y) return;
        int t = threadIdx.x;
        for (int idx = t; idx < DP_ * H_; idx += 256) {
            int d = idx >> 4, h = idx & 15;
            GhG[h * DP_ + d] = f2b(gamma[d] * wb[idx]);
        }
        if (t < 32) {
            int h = t & 15;
            const float* src = (t >= 16) ? beta : gamma;
            float s = 0.f;
            for (int d = 0; d < DP_; ++d) s = fmaf(src[d], wb[d * H_ + h], s);
            if (t >= 16) TsG[h] = s; else SsG[h] = s;
        }
        return;
    }
    __shared__ float tile[32][33];
    const float* in;
    unsigned short* out;
    int R, C;
    if (z < 4) {
        in = (z == 0) ? wq : (z == 1) ? wk : (z == 2) ? wv : wg;
        out = Wt + (long)z * 1024 * 384;
        R = 384; C = 1024;
    } else {
        in = wo; out = Wot; R = 1024; C = 384;
    }
    int c0 = blockIdx.x * 32, r0 = blockIdx.y * 32;
    if (c0 >= C || r0 >= R) return;
    int tx = threadIdx.x & 31, ty = threadIdx.x >> 5;
    #pragma unroll
    for (int i = ty; i < 32; i += 8)
        tile[i][tx] = in[(long)(r0 + i) * C + (c0 + tx)];
    __syncthreads();
    #pragma unroll
    for (int i = ty; i < 32; i += 8)
        out[(long)(c0 + i) * R + (r0 + tx)] = f2b(tile[tx][i]);
}

// ---------------- bias: LN(pairwise) @ w_bias + abb -> bf16 [b][h][i][j] ----
// v5 (reverted from v6): contiguous wave reads -> LDS (XOR-swizzled ds_write),
// swizzled ds_read_b128 fragments, register stats, MFMA dot. Block = 64 rows.
__global__ __launch_bounds__(256) void k_bias(const float* __restrict__ pw,
                                              const float* __restrict__ abb,
                                              const unsigned short* __restrict__ GhG,
                                              const float* __restrict__ SsG,
                                              const float* __restrict__ TsG,
                                              unsigned short* __restrict__ biasP) {
    __shared__ float Xs[64 * 128];                          // 32 KB, swizzled rows
    __shared__ float rsum[4][16] __attribute__((aligned(16)));
    __shared__ float rsq[4][16] __attribute__((aligned(16)));
    int t = threadIdx.x;
    int w = t >> 6, lane = t & 63;
    int lane15 = lane & 15, kg = lane >> 4;
    long p0 = (long)blockIdx.x * 64;            // first (b,i,j)-flat row
    int i_blk = (int)((p0 >> 9) & (N_ - 1));
    int j0 = (int)(p0 & (N_ - 1));
    long bb = p0 >> 18;

    // stage: linear 1KB-per-wave-instr global reads, XOR-swizzled LDS writes
    const char* src = (const char*)(pw + (p0 << 7));
    char* lds = (char*)Xs;
    #pragma unroll
    for (int c = 0; c < 8; ++c) {
        int L = c * 4096 + t * 16;
        int row = L >> 9, b = L & 511;
        uint4 v = *(const uint4*)(src + L);
        *(uint4*)(lds + (row << 9) + (b ^ ((row & 7) << 4))) = v;
    }

    // B fragments (heads) from global (4 KB, L2-hot)
    bf16x8 gb[4];
    #pragma unroll
    for (int kk = 0; kk < 4; ++kk)
        gb[kk] = *(const bf16x8*)&GhG[lane15 * DP_ + kk * 32 + kg * 8];
    float sh = SsG[lane15], th = TsG[lane15];
    __syncthreads();

    // fragments: row = w*16 + lane15, k-chunk kk, floats kg*8..+8 (swizzled read)
    int row = w * 16 + lane15;
    const char* rbase = lds + (row << 9);
    int sw = (lane15 & 7) << 4;
    f32x4 xa[4], xb4[4];
    #pragma unroll
    for (int kk = 0; kk < 4; ++kk) {
        int b0 = kk * 128 + kg * 32;
        xa[kk]  = *(const f32x4*)(rbase + ((b0) ^ sw));
        xb4[kk] = *(const f32x4*)(rbase + ((b0 + 16) ^ sw));
    }
    // local stats over this lane's 32 elems (exact fp32)
    float s = 0.f, q = 0.f;
    #pragma unroll
    for (int kk = 0; kk < 4; ++kk) {
        s += xa[kk][0] + xa[kk][1] + xa[kk][2] + xa[kk][3];
        s += xb4[kk][0] + xb4[kk][1] + xb4[kk][2] + xb4[kk][3];
        #pragma unroll
        for (int e = 0; e < 4; ++e) {
            q = fmaf(xa[kk][e], xa[kk][e], q);
            q = fmaf(xb4[kk][e], xb4[kk][e], q);
        }
    }
    // combine the 4 sibling lanes (same row)
    s += __shfl_xor(s, 16); s += __shfl_xor(s, 32);
    q += __shfl_xor(q, 16); q += __shfl_xor(q, 32);
    if (lane < 16) { rsum[w][lane15] = s; rsq[w][lane15] = q; }

    // convert fragments and MFMA
    f32x4 acc = {};
    #pragma unroll
    for (int kk = 0; kk < 4; ++kk) {
        bf16x8 a;
        unsigned short* ap = (unsigned short*)&a;
        ap[0] = f2b(xa[kk][0]);  ap[1] = f2b(xa[kk][1]);
        ap[2] = f2b(xa[kk][2]);  ap[3] = f2b(xa[kk][3]);
        ap[4] = f2b(xb4[kk][0]); ap[5] = f2b(xb4[kk][1]);
        ap[6] = f2b(xb4[kk][2]); ap[7] = f2b(xb4[kk][3]);
        acc = __builtin_amdgcn_mfma_f32_16x16x32_bf16(a, gb[kk], acc, 0, 0, 0);
    }
    // epilogue: lane holds col h=lane15, rows w*16 + kg*4 + r
    int jr = w * 16 + kg * 4;
    float4 rs = *(const float4*)&rsum[w][kg * 4];
    float4 rq = *(const float4*)&rsq[w][kg * 4];
    float4 av = *(const float4*)(abb + (long)i_blk * MAXSEQ + j0 + jr);
    unsigned short* planeBase = biasP + ((bb * H_ + lane15) * N_ + i_blk) * N_ + j0;
    ushort4 res;
    float mu, var;
    mu = rs.x * (1.f / DP_); var = fmaf(rq.x, 1.f / DP_, -mu * mu);
    res.x = f2b(fmaf(rsqrtf(var + 1e-5f), acc[0] - mu * sh, th + av.x));
    mu = rs.y * (1.f / DP_); var = fmaf(rq.y, 1.f / DP_, -mu * mu);
    res.y = f2b(fmaf(rsqrtf(var + 1e-5f), acc[1] - mu * sh, th + av.y));
    mu = rs.z * (1.f / DP_); var = fmaf(rq.z, 1.f / DP_, -mu * mu);
    res.z = f2b(fmaf(rsqrtf(var + 1e-5f), acc[2] - mu * sh, th + av.z));
    mu = rs.w * (1.f / DP_); var = fmaf(rq.w, 1.f / DP_, -mu * mu);
    res.w = f2b(fmaf(rsqrtf(var + 1e-5f), acc[3] - mu * sh, th + av.w));
    *(ushort4*)(planeBase + jr) = res;
}

// ---------------- QKVG projection GEMM (M=1024, N=4096, K=384) --------------
// v2: register-prefetch next K-tile (T14) — hides HBM latency under MFMA.
__global__ __launch_bounds__(256) void k_proj(const float* __restrict__ X,
                                              const unsigned short* __restrict__ Wt,
                                              unsigned short* __restrict__ Qb,
                                              unsigned short* __restrict__ Kb,
                                              unsigned short* __restrict__ Vt,
                                              unsigned short* __restrict__ Xg) {
    __shared__ unsigned short As[128][64 + PAD];
    __shared__ unsigned short Bs[128][64 + PAD];
    int m0 = blockIdx.x * 128;
    int n0 = blockIdx.y * 128;
    int t = threadIdx.x;
    int wave = t >> 6, lane = t & 63;
    int wr = wave >> 1, wc = wave & 1;
    int lane15 = lane & 15, kg = lane >> 4;
    int r = t >> 1, half = t & 1;
    f32x4 acc[4][4] = {};
    float4 xr[8];
    uint4 wreg[4];
    {
        const float4* src = (const float4*)(X + (long)(m0 + r) * DS_ + half * 32);
        #pragma unroll
        for (int ii = 0; ii < 8; ++ii) xr[ii] = src[ii];
        const uint4* wsrc = (const uint4*)(Wt + (long)(n0 + r) * DS_ + half * 32);
        #pragma unroll
        for (int ii = 0; ii < 4; ++ii) wreg[ii] = wsrc[ii];
    }
    for (int k0 = 0; k0 < DS_; k0 += 64) {
        __syncthreads();
        {
            unsigned short* dst = &As[r][half * 32];
            #pragma unroll
            for (int ii = 0; ii < 8; ++ii) {
                dst[ii * 4 + 0] = f2b(xr[ii].x); dst[ii * 4 + 1] = f2b(xr[ii].y);
                dst[ii * 4 + 2] = f2b(xr[ii].z); dst[ii * 4 + 3] = f2b(xr[ii].w);
            }
            uint4* wdst = (uint4*)&Bs[r][half * 32];
            wdst[0] = wreg[0]; wdst[1] = wreg[1]; wdst[2] = wreg[2]; wdst[3] = wreg[3];
        }
        __syncthreads();
        if (k0 + 64 < DS_) {            // prefetch next tile during compute
            const float4* src = (const float4*)(X + (long)(m0 + r) * DS_ + k0 + 64 + half * 32);
            #pragma unroll
            for (int ii = 0; ii < 8; ++ii) xr[ii] = src[ii];
            const uint4* wsrc = (const uint4*)(Wt + (long)(n0 + r) * DS_ + k0 + 64 + half * 32);
            #pragma unroll
            for (int ii = 0; ii < 4; ++ii) wreg[ii] = wsrc[ii];
        }
        #pragma unroll
        for (int ks = 0; ks < 2; ++ks) {
            bf16x8 a[4], bb[4];
            #pragma unroll
            for (int mf = 0; mf < 4; ++mf)
                a[mf] = *(const bf16x8*)&As[wr * 64 + mf * 16 + lane15][ks * 32 + kg * 8];
            #pragma unroll
            for (int nf = 0; nf < 4; ++nf)
                bb[nf] = *(const bf16x8*)&Bs[wc * 64 + nf * 16 + lane15][ks * 32 + kg * 8];
            #pragma unroll
            for (int mf = 0; mf < 4; ++mf)
                #pragma unroll
                for (int nf = 0; nf < 4; ++nf)
                    acc[mf][nf] = __builtin_amdgcn_mfma_f32_16x16x32_bf16(a[mf], bb[nf], acc[mf][nf], 0, 0, 0);
        }
    }
    int p = n0 >> 10;                 // which projection (q,k,v,g)
    int lgrp = lane >> 4;
    #pragma unroll
    for (int mf = 0; mf < 4; ++mf) {
        #pragma unroll
        for (int nf = 0; nf < 4; ++nf) {
            int col = n0 + wc * 64 + nf * 16 + lane15;
            int ch = col & 1023;
            int h = ch >> 6, dh = ch & 63;
            int row0 = m0 + wr * 64 + mf * 16 + lgrp * 4;
            if (p == 0 || p == 1) {
                unsigned short* base = (p == 0) ? Qb : Kb;
                float scl = (p == 0) ? 0.125f : 1.0f;
                #pragma unroll
                for (int rr = 0; rr < 4; ++rr) {
                    int rowx = row0 + rr;
                    int b = rowx >> 9, n = rowx & 511;
                    base[(((long)(b * 16 + h)) * 512 + n) * 64 + dh] = f2b(acc[mf][nf][rr] * scl);
                }
            } else if (p == 2) {
                int b = row0 >> 9, n = row0 & 511;
                ushort4 v;
                v.x = f2b(acc[mf][nf][0]); v.y = f2b(acc[mf][nf][1]);
                v.z = f2b(acc[mf][nf][2]); v.w = f2b(acc[mf][nf][3]);
                *(ushort4*)&Vt[(((long)(b * 16 + h)) * 64 + dh) * 512 + n] = v;
            } else {
                #pragma unroll
                for (int rr = 0; rr < 4; ++rr) {
                    int rowx = row0 + rr;
                    Xg[(long)rowx * 1024 + ch] = f2b(acc[mf][nf][rr]);
                }
            }
        }
    }
}

// ---------------- fused flash attention: S=Q@K^T+bias, softmax, P@V, gate ---
// v2: register-prefetch next K/V/B tile (T14); vectorized Bt reads + Ps writes.
__global__ __launch_bounds__(256) void k_flash(const unsigned short* __restrict__ Qb,
                                               const unsigned short* __restrict__ Kb,
                                               const unsigned short* __restrict__ Vt,
                                               const unsigned short* __restrict__ biasP,
                                               const unsigned short* __restrict__ Xg,
                                               unsigned short* __restrict__ Og) {
    __shared__ unsigned short Kt[64][72];    // [j][dh]
    __shared__ unsigned short Vs[64][72];    // [dh][j]
    __shared__ unsigned short Bt[64][72];    // [i][j] bias tile
    __shared__ unsigned short Ps[4][16][72]; // per-wave P [i][j]
    int bh = blockIdx.y;
    int b = bh >> 4, h = bh & 15;
    int i0 = blockIdx.x * 64;
    int t = threadIdx.x, w = t >> 6, lane = t & 63;
    int lane15 = lane & 15, lgrp = lane >> 4;
    int r0_ = t >> 3, c0_ = t & 7;
    int r1_ = (256 + t) >> 3, c1_ = t & 7;

    bf16x8 qf[2];
    #pragma unroll
    for (int kk = 0; kk < 2; ++kk)
        qf[kk] = *(const bf16x8*)&Qb[((long)bh * 512 + i0 + w * 16 + lane15) * 64 + kk * 32 + lgrp * 8];

    float m_run = -1e30f, l_run = 0.f;
    f32x4 o[4] = {};   // o[nf][r] = O[i0+w*16+lgrp*4+r][nf*16+lane15]

    uint4 rk[2], rv[2], rb[2];
#define FL_LOAD(JT) do { int jq = (JT) * 64; \
    rk[0] = *(const uint4*)&Kb[((long)bh * 512 + jq + r0_) * 64 + c0_ * 8]; \
    rv[0] = *(const uint4*)&Vt[((long)bh * 64 + r0_) * 512 + jq + c0_ * 8]; \
    rb[0] = *(const uint4*)&biasP[(((long)bh * 512) + i0 + r0_) * 512 + jq + c0_ * 8]; \
    rk[1] = *(const uint4*)&Kb[((long)bh * 512 + jq + r1_) * 64 + c1_ * 8]; \
    rv[1] = *(const uint4*)&Vt[((long)bh * 64 + r1_) * 512 + jq + c1_ * 8]; \
    rb[1] = *(const uint4*)&biasP[(((long)bh * 512) + i0 + r1_) * 512 + jq + c1_ * 8]; } while (0)

    FL_LOAD(0);
    for (int jt = 0; jt < 8; ++jt) {
        __syncthreads();   // previous tile fully consumed
        *(uint4*)&Kt[r0_][c0_ * 8] = rk[0];
        *(uint4*)&Vs[r0_][c0_ * 8] = rv[0];
        *(uint4*)&Bt[r0_][c0_ * 8] = rb[0];
        *(uint4*)&Kt[r1_][c1_ * 8] = rk[1];
        *(uint4*)&Vs[r1_][c1_ * 8] = rv[1];
        *(uint4*)&Bt[r1_][c1_ * 8] = rb[1];
        __syncthreads();
        if (jt < 7) FL_LOAD(jt + 1);    // issue next loads; hide under compute

        // S^T[j][i]: A = K[j][dh], B = Q[i][dh]
        f32x4 s[4];
        #pragma unroll
        for (int nf = 0; nf < 4; ++nf) {
            f32x4 z = {};
            #pragma unroll
            for (int kk = 0; kk < 2; ++kk) {
                bf16x8 af = *(const bf16x8*)&Kt[nf * 16 + lane15][kk * 32 + lgrp * 8];
                z = __builtin_amdgcn_mfma_f32_16x16x32_bf16(af, qf[kk], z, 0, 0, 0);
            }
            s[nf] = z;
        }
        // bias add (vector b64 reads)
        #pragma unroll
        for (int nf = 0; nf < 4; ++nf) {
            ushort4 bv = *(const ushort4*)&Bt[w * 16 + lane15][nf * 16 + lgrp * 4];
            s[nf][0] += b2f(bv.x); s[nf][1] += b2f(bv.y);
            s[nf][2] += b2f(bv.z); s[nf][3] += b2f(bv.w);
        }

        // online softmax, lane owns row i = lane15 within wave
        float pmax = s[0][0];
        #pragma unroll
        for (int nf = 0; nf < 4; ++nf)
            #pragma unroll
            for (int rr = 0; rr < 4; ++rr) pmax = fmaxf(pmax, s[nf][rr]);
        pmax = fmaxf(pmax, __shfl_xor(pmax, 16));
        pmax = fmaxf(pmax, __shfl_xor(pmax, 32));
        float m_new = fmaxf(m_run, pmax);
        float scale = __expf(m_run - m_new);
        float psum = 0.f;
        #pragma unroll
        for (int nf = 0; nf < 4; ++nf)
            #pragma unroll
            for (int rr = 0; rr < 4; ++rr) {
                s[nf][rr] = __expf(s[nf][rr] - m_new);
                psum += s[nf][rr];
            }
        psum += __shfl_xor(psum, 16);
        psum += __shfl_xor(psum, 32);
        l_run = l_run * scale + psum;
        m_run = m_new;
        #pragma unroll
        for (int rr = 0; rr < 4; ++rr) {
            float sc = __shfl(scale, lgrp * 4 + rr);
            #pragma unroll
            for (int nf = 0; nf < 4; ++nf) o[nf][rr] *= sc;
        }
        // P -> LDS (vector b64 writes)
        #pragma unroll
        for (int nf = 0; nf < 4; ++nf) {
            ushort4 pv_;
            pv_.x = f2b(s[nf][0]); pv_.y = f2b(s[nf][1]);
            pv_.z = f2b(s[nf][2]); pv_.w = f2b(s[nf][3]);
            *(ushort4*)&Ps[w][lane15][nf * 16 + lgrp * 4] = pv_;
        }
        // PV: A = P[i][j], B = V[dh][j]
        #pragma unroll
        for (int kk = 0; kk < 2; ++kk) {
            bf16x8 pa = *(const bf16x8*)&Ps[w][lane15][kk * 32 + lgrp * 8];
            #pragma unroll
            for (int nf = 0; nf < 4; ++nf) {
                bf16x8 vb = *(const bf16x8*)&Vs[nf * 16 + lane15][kk * 32 + lgrp * 8];
                o[nf] = __builtin_amdgcn_mfma_f32_16x16x32_bf16(pa, vb, o[nf], 0, 0, 0);
            }
        }
    }
#undef FL_LOAD
    // epilogue: divide by l, sigmoid gate, store
    #pragma unroll
    for (int rr = 0; rr < 4; ++rr) {
        float l_r = __shfl(l_run, lgrp * 4 + rr);
        float inv = 1.f / l_r;
        long grow = (long)b * 512 + i0 + w * 16 + lgrp * 4 + rr;
        #pragma unroll
        for (int nf = 0; nf < 4; ++nf) {
            int dh = nf * 16 + lane15;
            float xgv = b2f(Xg[grow * 1024 + h * 64 + dh]);
            float gate = 1.f / (1.f + __expf(-xgv));
            Og[grow * 1024 + h * 64 + dh] = f2b(o[nf][rr] * inv * gate);
        }
    }
}

// ---------------- output GEMM: out = Og @ w_o (M=1024,N=384,K=1024) ---------
// v2: register-prefetch next K-tile (24 blocks, latency was fully exposed).
__global__ __launch_bounds__(256) void k_out(const unsigned short* __restrict__ Og,
                                             const unsigned short* __restrict__ Wot,
                                             float* __restrict__ out) {
    __shared__ unsigned short As[128][64 + PAD];
    __shared__ unsigned short Bs[128][64 + PAD];
    int m0 = blockIdx.x * 128, n0 = blockIdx.y * 128;
    int t = threadIdx.x, wave = t >> 6, lane = t & 63;
    int wr = wave >> 1, wc = wave & 1;
    int lane15 = lane & 15, kg = lane >> 4;
    int r = t >> 1, half = t & 1;
    f32x4 acc[4][4] = {};
    uint4 ar[4], br[4];
    {
        const uint4* src = (const uint4*)(Og + (long)(m0 + r) * 1024 + half * 32);
        const uint4* wsrc = (const uint4*)(Wot + (long)(n0 + r) * 1024 + half * 32);
        #pragma unroll
        for (int ii = 0; ii < 4; ++ii) { ar[ii] = src[ii]; br[ii] = wsrc[ii]; }
    }
    for (int k0 = 0; k0 < 1024; k0 += 64) {
        __syncthreads();
        {
            uint4* dst = (uint4*)&As[r][half * 32];
            uint4* wdst = (uint4*)&Bs[r][half * 32];
            #pragma unroll
            for (int ii = 0; ii < 4; ++ii) { dst[ii] = ar[ii]; wdst[ii] = br[ii]; }
        }
        __syncthreads();
        if (k0 + 64 < 1024) {
            const uint4* src = (const uint4*)(Og + (long)(m0 + r) * 1024 + k0 + 64 + half * 32);
            const uint4* wsrc = (const uint4*)(Wot + (long)(n0 + r) * 1024 + k0 + 64 + half * 32);
            #pragma unroll
            for (int ii = 0; ii < 4; ++ii) { ar[ii] = src[ii]; br[ii] = wsrc[ii]; }
        }
        #pragma unroll
        for (int ks = 0; ks < 2; ++ks) {
            bf16x8 a[4], bb[4];
            #pragma unroll
            for (int mf = 0; mf < 4; ++mf)
                a[mf] = *(const bf16x8*)&As[wr * 64 + mf * 16 + lane15][ks * 32 + kg * 8];
            #pragma unroll
            for (int nf = 0; nf < 4; ++nf)
                bb[nf] = *(const bf16x8*)&Bs[wc * 64 + nf * 16 + lane15][ks * 32 + kg * 8];
            #pragma unroll
            for (int mf = 0; mf < 4; ++mf)
                #pragma unroll
                for (int nf = 0; nf < 4; ++nf)
                    acc[mf][nf] = __builtin_amdgcn_mfma_f32_16x16x32_bf16(a[mf], bb[nf], acc[mf][nf], 0, 0, 0);
        }
    }
    int lgrp = lane >> 4;
    #pragma unroll
    for (int mf = 0; mf < 4; ++mf) {
        #pragma unroll
        for (int nf = 0; nf < 4; ++nf) {
            int col = n0 + wc * 64 + nf * 16 + lane15;
            int row0 = m0 + wr * 64 + mf * 16 + lgrp * 4;
            #pragma unroll
            for (int rr = 0; rr < 4; ++rr)
                out[(long)(row0 + rr) * DS_ + col] = acc[mf][nf][rr];
        }
    }
}

extern "C" void kernel_launch(void* const* d_in, const int* in_sizes, int n_in,
                              void* d_out, int out_size, void* d_ws, size_t ws_size,
                              hipStream_t stream) {
    const float* single = (const float*)d_in[0];
    const float* pw     = (const float*)d_in[1];
    const float* gamma  = (const float*)d_in[2];
    const float* beta   = (const float*)d_in[3];
    const float* wb     = (const float*)d_in[4];
    const float* abb    = (const float*)d_in[5];
    const float* wq     = (const float*)d_in[6];
    const float* wk     = (const float*)d_in[7];
    const float* wv     = (const float*)d_in[8];
    const float* wg     = (const float*)d_in[9];
    const float* wo     = (const float*)d_in[10];
    float* out = (float*)d_out;
    char* ws = (char*)d_ws;

    unsigned short* SP  = (unsigned short*)(ws);                 // 16 MB bias [b][h][i][j]
    unsigned short* Qb  = (unsigned short*)(ws + 16777216);      // 2 MB (pre-scaled 0.125)
    unsigned short* Kb  = (unsigned short*)(ws + 18874368);      // 2 MB
    unsigned short* Vt  = (unsigned short*)(ws + 20971520);      // 2 MB [b][h][dh][n]
    unsigned short* Xg  = (unsigned short*)(ws + 23068672);      // 2 MB
    unsigned short* Og  = (unsigned short*)(ws + 25165824);      // 2 MB
    unsigned short* Wt  = (unsigned short*)(ws + 27262976);      // 3 MB [4*1024][384]
    unsigned short* Wot = (unsigned short*)(ws + 30408704);      // 0.75 MB [384][1024]
    unsigned short* GhG = (unsigned short*)(ws + 31195136);      // 4 KB  [16][128] bf16
    float* SsG          = (float*)(ws + 31199232);               // 64 B
    float* TsG          = (float*)(ws + 31199296);               // 64 B

    k_transpose_all<<<dim3(32, 32, 6), 256, 0, stream>>>(wq, wk, wv, wg, wo,
                                                         gamma, beta, wb,
                                                         Wt, Wot, GhG, SsG, TsG);
    k_bias<<<8192, 256, 0, stream>>>(pw, abb, GhG, SsG, TsG, SP);
    k_proj<<<dim3(8, 32), 256, 0, stream>>>(single, Wt, Qb, Kb, Vt, Xg);
    k_flash<<<dim3(8, 32), 256, 0, stream>>>(Qb, Kb, Vt, SP, Xg, Og);
    k_out<<<dim3(8, 3), 256, 0, stream>>>(Og, Wot, out);
}

// Round 12
// 120.847 us; speedup vs baseline: 30.5432x; 1.3721x over previous
//
#include <hip/hip_runtime.h>
#include <hip/hip_bf16.h>

#define B_ 2
#define N_ 512
#define DS_ 384
#define DP_ 128
#define H_ 16
#define DH_ 64
#define DI_ 1024
#define MAXSEQ 2048
#define PAD 8

typedef float f32x4 __attribute__((ext_vector_type(4)));
typedef short bf16x8 __attribute__((ext_vector_type(8)));

__device__ __forceinline__ unsigned short f2b(float f) {
    unsigned int u = __builtin_bit_cast(unsigned int, f);
    u += 0x7FFFu + ((u >> 16) & 1u);
    return (unsigned short)(u >> 16);
}
__device__ __forceinline__ float b2f(unsigned short s) {
    unsigned int u = ((unsigned int)s) << 16;
    return __builtin_bit_cast(float, u);
}

// -------- weight transposes + bias-GEMM prep (Gh = gamma*w, Ssum, Tsum) -----
__global__ __launch_bounds__(256) void k_transpose_all(const float* __restrict__ wq,
                                                       const float* __restrict__ wk,
                                                       const float* __restrict__ wv,
                                                       const float* __restrict__ wg,
                                                       const float* __restrict__ wo,
                                                       const float* __restrict__ gamma,
                                                       const float* __restrict__ beta,
                                                       const float* __restrict__ wb,
                                                       unsigned short* __restrict__ Wt,
                                                       unsigned short* __restrict__ Wot,
                                                       unsigned short* __restrict__ GhG,
                                                       float* __restrict__ SsG,
                                                       float* __restrict__ TsG) {
    int z = blockIdx.z;
    if (z == 5) {                       // prep for k_bias (one block only)
        if (blockIdx.x || blockIdx.y) return;
        int t = threadIdx.x;
        for (int idx = t; idx < DP_ * H_; idx += 256) {
            int d = idx >> 4, h = idx & 15;
            GhG[h * DP_ + d] = f2b(gamma[d] * wb[idx]);
        }
        if (t < 32) {
            int h = t & 15;
            const float* src = (t >= 16) ? beta : gamma;
            float s = 0.f;
            for (int d = 0; d < DP_; ++d) s = fmaf(src[d], wb[d * H_ + h], s);
            if (t >= 16) TsG[h] = s; else SsG[h] = s;
        }
        return;
    }
    __shared__ float tile[32][33];
    const float* in;
    unsigned short* out;
    int R, C;
    if (z < 4) {
        in = (z == 0) ? wq : (z == 1) ? wk : (z == 2) ? wv : wg;
        out = Wt + (long)z * 1024 * 384;
        R = 384; C = 1024;
    } else {
        in = wo; out = Wot; R = 1024; C = 384;
    }
    int c0 = blockIdx.x * 32, r0 = blockIdx.y * 32;
    if (c0 >= C || r0 >= R) return;
    int tx = threadIdx.x & 31, ty = threadIdx.x >> 5;
    #pragma unroll
    for (int i = ty; i < 32; i += 8)
        tile[i][tx] = in[(long)(r0 + i) * C + (c0 + tx)];
    __syncthreads();
    #pragma unroll
    for (int i = ty; i < 32; i += 8)
        out[(long)(c0 + i) * R + (r0 + tx)] = f2b(tile[tx][i]);
}

// ---------------- bias: LN(pairwise) @ w_bias + abb -> bf16 [b][h][i][j] ----
// v5 (known-good): contiguous wave reads -> LDS (XOR-swizzled ds_write),
// swizzled ds_read_b128 fragments, register stats, MFMA dot. Block = 64 rows.
__global__ __launch_bounds__(256) void k_bias(const float* __restrict__ pw,
                                              const float* __restrict__ abb,
                                              const unsigned short* __restrict__ GhG,
                                              const float* __restrict__ SsG,
                                              const float* __restrict__ TsG,
                                              unsigned short* __restrict__ biasP) {
    __shared__ float Xs[64 * 128];                          // 32 KB, swizzled rows
    __shared__ float rsum[4][16] __attribute__((aligned(16)));
    __shared__ float rsq[4][16] __attribute__((aligned(16)));
    int t = threadIdx.x;
    int w = t >> 6, lane = t & 63;
    int lane15 = lane & 15, kg = lane >> 4;
    long p0 = (long)blockIdx.x * 64;            // first (b,i,j)-flat row
    int i_blk = (int)((p0 >> 9) & (N_ - 1));
    int j0 = (int)(p0 & (N_ - 1));
    long bb = p0 >> 18;

    // stage: linear 1KB-per-wave-instr global reads, XOR-swizzled LDS writes
    const char* src = (const char*)(pw + (p0 << 7));
    char* lds = (char*)Xs;
    #pragma unroll
    for (int c = 0; c < 8; ++c) {
        int L = c * 4096 + t * 16;
        int row = L >> 9, b = L & 511;
        uint4 v = *(const uint4*)(src + L);
        *(uint4*)(lds + (row << 9) + (b ^ ((row & 7) << 4))) = v;
    }

    // B fragments (heads) from global (4 KB, L2-hot)
    bf16x8 gb[4];
    #pragma unroll
    for (int kk = 0; kk < 4; ++kk)
        gb[kk] = *(const bf16x8*)&GhG[lane15 * DP_ + kk * 32 + kg * 8];
    float sh = SsG[lane15], th = TsG[lane15];
    __syncthreads();

    // fragments: row = w*16 + lane15, k-chunk kk, floats kg*8..+8 (swizzled read)
    int row = w * 16 + lane15;
    const char* rbase = lds + (row << 9);
    int sw = (lane15 & 7) << 4;
    f32x4 xa[4], xb4[4];
    #pragma unroll
    for (int kk = 0; kk < 4; ++kk) {
        int b0 = kk * 128 + kg * 32;
        xa[kk]  = *(const f32x4*)(rbase + ((b0) ^ sw));
        xb4[kk] = *(const f32x4*)(rbase + ((b0 + 16) ^ sw));
    }
    // local stats over this lane's 32 elems (exact fp32)
    float s = 0.f, q = 0.f;
    #pragma unroll
    for (int kk = 0; kk < 4; ++kk) {
        s += xa[kk][0] + xa[kk][1] + xa[kk][2] + xa[kk][3];
        s += xb4[kk][0] + xb4[kk][1] + xb4[kk][2] + xb4[kk][3];
        #pragma unroll
        for (int e = 0; e < 4; ++e) {
            q = fmaf(xa[kk][e], xa[kk][e], q);
            q = fmaf(xb4[kk][e], xb4[kk][e], q);
        }
    }
    s += __shfl_xor(s, 16); s += __shfl_xor(s, 32);
    q += __shfl_xor(q, 16); q += __shfl_xor(q, 32);
    if (lane < 16) { rsum[w][lane15] = s; rsq[w][lane15] = q; }

    // convert fragments and MFMA
    f32x4 acc = {};
    #pragma unroll
    for (int kk = 0; kk < 4; ++kk) {
        bf16x8 a;
        unsigned short* ap = (unsigned short*)&a;
        ap[0] = f2b(xa[kk][0]);  ap[1] = f2b(xa[kk][1]);
        ap[2] = f2b(xa[kk][2]);  ap[3] = f2b(xa[kk][3]);
        ap[4] = f2b(xb4[kk][0]); ap[5] = f2b(xb4[kk][1]);
        ap[6] = f2b(xb4[kk][2]); ap[7] = f2b(xb4[kk][3]);
        acc = __builtin_amdgcn_mfma_f32_16x16x32_bf16(a, gb[kk], acc, 0, 0, 0);
    }
    // epilogue: lane holds col h=lane15, rows w*16 + kg*4 + r
    int jr = w * 16 + kg * 4;
    float4 rs = *(const float4*)&rsum[w][kg * 4];
    float4 rq = *(const float4*)&rsq[w][kg * 4];
    float4 av = *(const float4*)(abb + (long)i_blk * MAXSEQ + j0 + jr);
    unsigned short* planeBase = biasP + ((bb * H_ + lane15) * N_ + i_blk) * N_ + j0;
    ushort4 res;
    float mu, var;
    mu = rs.x * (1.f / DP_); var = fmaf(rq.x, 1.f / DP_, -mu * mu);
    res.x = f2b(fmaf(rsqrtf(var + 1e-5f), acc[0] - mu * sh, th + av.x));
    mu = rs.y * (1.f / DP_); var = fmaf(rq.y, 1.f / DP_, -mu * mu);
    res.y = f2b(fmaf(rsqrtf(var + 1e-5f), acc[1] - mu * sh, th + av.y));
    mu = rs.z * (1.f / DP_); var = fmaf(rq.z, 1.f / DP_, -mu * mu);
    res.z = f2b(fmaf(rsqrtf(var + 1e-5f), acc[2] - mu * sh, th + av.z));
    mu = rs.w * (1.f / DP_); var = fmaf(rq.w, 1.f / DP_, -mu * mu);
    res.w = f2b(fmaf(rsqrtf(var + 1e-5f), acc[3] - mu * sh, th + av.w));
    *(ushort4*)(planeBase + jr) = res;
}

// ---------------- QKVG projection GEMM (M=1024, N=4096, K=384) --------------
// R7 form (no prefetch). Q is pre-scaled by 0.125.
__global__ __launch_bounds__(256) void k_proj(const float* __restrict__ X,
                                              const unsigned short* __restrict__ Wt,
                                              unsigned short* __restrict__ Qb,
                                              unsigned short* __restrict__ Kb,
                                              unsigned short* __restrict__ Vt,
                                              unsigned short* __restrict__ Xg) {
    __shared__ unsigned short As[128][64 + PAD];
    __shared__ unsigned short Bs[128][64 + PAD];
    int m0 = blockIdx.x * 128;
    int n0 = blockIdx.y * 128;
    int t = threadIdx.x;
    int wave = t >> 6, lane = t & 63;
    int wr = wave >> 1, wc = wave & 1;
    int lane15 = lane & 15, kg = lane >> 4;
    f32x4 acc[4][4] = {};
    for (int k0 = 0; k0 < DS_; k0 += 64) {
        __syncthreads();
        {
            int r = t >> 1, half = t & 1;
            const float4* src = (const float4*)(X + (long)(m0 + r) * DS_ + k0 + half * 32);
            unsigned short* dst = &As[r][half * 32];
            #pragma unroll
            for (int ii = 0; ii < 8; ++ii) {
                float4 v = src[ii];
                dst[ii * 4 + 0] = f2b(v.x); dst[ii * 4 + 1] = f2b(v.y);
                dst[ii * 4 + 2] = f2b(v.z); dst[ii * 4 + 3] = f2b(v.w);
            }
            const uint4* wsrc = (const uint4*)(Wt + (long)(n0 + r) * DS_ + k0 + half * 32);
            uint4* wdst = (uint4*)&Bs[r][half * 32];
            wdst[0] = wsrc[0]; wdst[1] = wsrc[1]; wdst[2] = wsrc[2]; wdst[3] = wsrc[3];
        }
        __syncthreads();
        #pragma unroll
        for (int ks = 0; ks < 2; ++ks) {
            bf16x8 a[4], bb[4];
            #pragma unroll
            for (int mf = 0; mf < 4; ++mf)
                a[mf] = *(const bf16x8*)&As[wr * 64 + mf * 16 + lane15][ks * 32 + kg * 8];
            #pragma unroll
            for (int nf = 0; nf < 4; ++nf)
                bb[nf] = *(const bf16x8*)&Bs[wc * 64 + nf * 16 + lane15][ks * 32 + kg * 8];
            #pragma unroll
            for (int mf = 0; mf < 4; ++mf)
                #pragma unroll
                for (int nf = 0; nf < 4; ++nf)
                    acc[mf][nf] = __builtin_amdgcn_mfma_f32_16x16x32_bf16(a[mf], bb[nf], acc[mf][nf], 0, 0, 0);
        }
    }
    int p = n0 >> 10;                 // which projection (q,k,v,g)
    int lgrp = lane >> 4;
    #pragma unroll
    for (int mf = 0; mf < 4; ++mf) {
        #pragma unroll
        for (int nf = 0; nf < 4; ++nf) {
            int col = n0 + wc * 64 + nf * 16 + lane15;
            int ch = col & 1023;
            int h = ch >> 6, dh = ch & 63;
            int row0 = m0 + wr * 64 + mf * 16 + lgrp * 4;
            if (p == 0 || p == 1) {
                unsigned short* base = (p == 0) ? Qb : Kb;
                float scl = (p == 0) ? 0.125f : 1.0f;
                #pragma unroll
                for (int rr = 0; rr < 4; ++rr) {
                    int rowx = row0 + rr;
                    int b = rowx >> 9, n = rowx & 511;
                    base[(((long)(b * 16 + h)) * 512 + n) * 64 + dh] = f2b(acc[mf][nf][rr] * scl);
                }
            } else if (p == 2) {
                int b = row0 >> 9, n = row0 & 511;
                ushort4 v;
                v.x = f2b(acc[mf][nf][0]); v.y = f2b(acc[mf][nf][1]);
                v.z = f2b(acc[mf][nf][2]); v.w = f2b(acc[mf][nf][3]);
                *(ushort4*)&Vt[(((long)(b * 16 + h)) * 64 + dh) * 512 + n] = v;
            } else {
                #pragma unroll
                for (int rr = 0; rr < 4; ++rr) {
                    int rowx = row0 + rr;
                    Xg[(long)rowx * 1024 + ch] = f2b(acc[mf][nf][rr]);
                }
            }
        }
    }
}

// ---------------- fused flash attention: S=Q@K^T+bias, softmax, P@V, gate ---
// v3: 512 threads = 4 i-groups x 2 j-groups (split-softmax). Each j-group
// handles 4 of the 8 KV tiles; states merged at the end via LDS.
// Grid (8 i-blocks, 32 bh) -> 2 waves/SIMD (was 1).
__global__ __launch_bounds__(512) void k_flash(const unsigned short* __restrict__ Qb,
                                               const unsigned short* __restrict__ Kb,
                                               const unsigned short* __restrict__ Vt,
                                               const unsigned short* __restrict__ biasP,
                                               const unsigned short* __restrict__ Xg,
                                               unsigned short* __restrict__ Og) {
    __shared__ unsigned short Kt[2][64][72];   // [jg][j][dh]
    __shared__ unsigned short Vs[2][64][72];   // [jg][dh][j]
    __shared__ unsigned short Bt[2][64][72];   // [jg][i][j]
    __shared__ unsigned short Ps[8][16][72];   // per-wave P [i][j]
    __shared__ float Mscr[4][16], Lscr[4][16];
    __shared__ float Oscr[4][16][64];          // [g][row][dh] from j-group 1
    int bh = blockIdx.y;
    int b = bh >> 4, h = bh & 15;
    int i0 = blockIdx.x * 64;
    int t = threadIdx.x, w = t >> 6, lane = t & 63;
    int g = w & 3, jg = w >> 2;
    int lane15 = lane & 15, lgrp = lane >> 4;
    int tl = t & 255;
    int rs_ = tl >> 3, cs_ = tl & 7;           // staging row/col within group

    // Q fragments (B-operand), row i = i0 + g*16 + lane15, pre-scaled by 0.125
    bf16x8 qf[2];
    #pragma unroll
    for (int kk = 0; kk < 2; ++kk)
        qf[kk] = *(const bf16x8*)&Qb[((long)bh * 512 + i0 + g * 16 + lane15) * 64 + kk * 32 + lgrp * 8];

    float m_run = -1e30f, l_run = 0.f;
    f32x4 o[4] = {};   // o[nf][rr] = O_un[i0+g*16+lgrp*4+rr][nf*16+lane15]

    for (int jtl = 0; jtl < 4; ++jtl) {
        int j0 = (jg * 4 + jtl) * 64;
        __syncthreads();   // previous tile fully consumed (both groups)
        {
            *(uint4*)&Kt[jg][rs_][cs_ * 8] = *(const uint4*)&Kb[((long)bh * 512 + j0 + rs_) * 64 + cs_ * 8];
            *(uint4*)&Vs[jg][rs_][cs_ * 8] = *(const uint4*)&Vt[((long)bh * 64 + rs_) * 512 + j0 + cs_ * 8];
            *(uint4*)&Bt[jg][rs_][cs_ * 8] = *(const uint4*)&biasP[((long)bh * 512 + i0 + rs_) * 512 + j0 + cs_ * 8];
            int r2 = rs_ + 32;
            *(uint4*)&Kt[jg][r2][cs_ * 8] = *(const uint4*)&Kb[((long)bh * 512 + j0 + r2) * 64 + cs_ * 8];
            *(uint4*)&Vs[jg][r2][cs_ * 8] = *(const uint4*)&Vt[((long)bh * 64 + r2) * 512 + j0 + cs_ * 8];
            *(uint4*)&Bt[jg][r2][cs_ * 8] = *(const uint4*)&biasP[((long)bh * 512 + i0 + r2) * 512 + j0 + cs_ * 8];
        }
        __syncthreads();

        // S^T[j][i]: A = K[j][dh], B = Q[i][dh]  -> lane holds row i=lane15
        f32x4 s[4];
        #pragma unroll
        for (int nf = 0; nf < 4; ++nf) {
            f32x4 z = {};
            #pragma unroll
            for (int kk = 0; kk < 2; ++kk) {
                bf16x8 af = *(const bf16x8*)&Kt[jg][nf * 16 + lane15][kk * 32 + lgrp * 8];
                z = __builtin_amdgcn_mfma_f32_16x16x32_bf16(af, qf[kk], z, 0, 0, 0);
            }
            s[nf] = z;
        }
        // bias add (vector b64 reads): s[nf][rr] is S[i=lane15][j0+nf*16+lgrp*4+rr]
        #pragma unroll
        for (int nf = 0; nf < 4; ++nf) {
            ushort4 bv = *(const ushort4*)&Bt[jg][g * 16 + lane15][nf * 16 + lgrp * 4];
            s[nf][0] += b2f(bv.x); s[nf][1] += b2f(bv.y);
            s[nf][2] += b2f(bv.z); s[nf][3] += b2f(bv.w);
        }

        // online softmax (within this j-group)
        float pmax = s[0][0];
        #pragma unroll
        for (int nf = 0; nf < 4; ++nf)
            #pragma unroll
            for (int rr = 0; rr < 4; ++rr) pmax = fmaxf(pmax, s[nf][rr]);
        pmax = fmaxf(pmax, __shfl_xor(pmax, 16));
        pmax = fmaxf(pmax, __shfl_xor(pmax, 32));
        float m_new = fmaxf(m_run, pmax);
        float scale = __expf(m_run - m_new);
        float psum = 0.f;
        #pragma unroll
        for (int nf = 0; nf < 4; ++nf)
            #pragma unroll
            for (int rr = 0; rr < 4; ++rr) {
                s[nf][rr] = __expf(s[nf][rr] - m_new);
                psum += s[nf][rr];
            }
        psum += __shfl_xor(psum, 16);
        psum += __shfl_xor(psum, 32);
        l_run = l_run * scale + psum;
        m_run = m_new;
        #pragma unroll
        for (int rr = 0; rr < 4; ++rr) {
            float sc = __shfl(scale, lgrp * 4 + rr);
            #pragma unroll
            for (int nf = 0; nf < 4; ++nf) o[nf][rr] *= sc;
        }
        // P -> LDS (vector b64 writes)
        #pragma unroll
        for (int nf = 0; nf < 4; ++nf) {
            ushort4 pv_;
            pv_.x = f2b(s[nf][0]); pv_.y = f2b(s[nf][1]);
            pv_.z = f2b(s[nf][2]); pv_.w = f2b(s[nf][3]);
            *(ushort4*)&Ps[w][lane15][nf * 16 + lgrp * 4] = pv_;
        }
        // PV: A = P[i][j], B = V[dh][j]
        #pragma unroll
        for (int kk = 0; kk < 2; ++kk) {
            bf16x8 pa = *(const bf16x8*)&Ps[w][lane15][kk * 32 + lgrp * 8];
            #pragma unroll
            for (int nf = 0; nf < 4; ++nf) {
                bf16x8 vb = *(const bf16x8*)&Vs[jg][nf * 16 + lane15][kk * 32 + lgrp * 8];
                o[nf] = __builtin_amdgcn_mfma_f32_16x16x32_bf16(pa, vb, o[nf], 0, 0, 0);
            }
        }
    }

    // ---- split-softmax merge: j-group 1 publishes, j-group 0 merges+stores
    __syncthreads();
    if (jg == 1) {
        if (lane < 16) { Mscr[g][lane] = m_run; Lscr[g][lane] = l_run; }
        #pragma unroll
        for (int nf = 0; nf < 4; ++nf)
            #pragma unroll
            for (int rr = 0; rr < 4; ++rr)
                Oscr[g][lgrp * 4 + rr][nf * 16 + lane15] = o[nf][rr];
    }
    __syncthreads();
    if (jg == 0) {
        #pragma unroll
        for (int rr = 0; rr < 4; ++rr) {
            int row = lgrp * 4 + rr;
            float m1 = __shfl(m_run, row);
            float l1 = __shfl(l_run, row);
            float m2 = Mscr[g][row];
            float l2 = Lscr[g][row];
            float mm = fmaxf(m1, m2);
            float e1 = __expf(m1 - mm), e2 = __expf(m2 - mm);
            float inv = 1.f / (l1 * e1 + l2 * e2);
            long grow = (long)b * 512 + i0 + g * 16 + row;
            #pragma unroll
            for (int nf = 0; nf < 4; ++nf) {
                int dh = nf * 16 + lane15;
                float o2 = Oscr[g][row][dh];
                float val = (o[nf][rr] * e1 + o2 * e2) * inv;
                float xgv = b2f(Xg[grow * 1024 + h * 64 + dh]);
                float gate = 1.f / (1.f + __expf(-xgv));
                Og[grow * 1024 + h * 64 + dh] = f2b(val * gate);
            }
        }
    }
}

// ---------------- output GEMM: out = Og @ w_o (M=1024,N=384,K=1024) ---------
// v3: 64x64 tiles -> 96 blocks (was 24). 2x2 waves, each 32x32.
__global__ __launch_bounds__(256) void k_out(const unsigned short* __restrict__ Og,
                                             const unsigned short* __restrict__ Wot,
                                             float* __restrict__ out) {
    __shared__ unsigned short As[64][64 + PAD];
    __shared__ unsigned short Bs[64][64 + PAD];
    int m0 = blockIdx.x * 64, n0 = blockIdx.y * 64;
    int t = threadIdx.x, wave = t >> 6, lane = t & 63;
    int wr = wave >> 1, wc = wave & 1;
    int lane15 = lane & 15, kg = lane >> 4;
    f32x4 acc[2][2] = {};
    for (int k0 = 0; k0 < 1024; k0 += 64) {
        __syncthreads();
        {
            int r = t >> 2, qd = t & 3;      // 64 rows, 4 threads/row, 16 ushorts each
            const uint4* s1 = (const uint4*)(Og + (long)(m0 + r) * 1024 + k0 + qd * 16);
            uint4* d1 = (uint4*)&As[r][qd * 16];
            d1[0] = s1[0]; d1[1] = s1[1];
            const uint4* s2 = (const uint4*)(Wot + (long)(n0 + r) * 1024 + k0 + qd * 16);
            uint4* d2 = (uint4*)&Bs[r][qd * 16];
            d2[0] = s2[0]; d2[1] = s2[1];
        }
        __syncthreads();
        #pragma unroll
        for (int ks = 0; ks < 2; ++ks) {
            bf16x8 a[2], bb[2];
            #pragma unroll
            for (int mf = 0; mf < 2; ++mf)
                a[mf] = *(const bf16x8*)&As[wr * 32 + mf * 16 + lane15][ks * 32 + kg * 8];
            #pragma unroll
            for (int nf = 0; nf < 2; ++nf)
                bb[nf] = *(const bf16x8*)&Bs[wc * 32 + nf * 16 + lane15][ks * 32 + kg * 8];
            #pragma unroll
            for (int mf = 0; mf < 2; ++mf)
                #pragma unroll
                for (int nf = 0; nf < 2; ++nf)
                    acc[mf][nf] = __builtin_amdgcn_mfma_f32_16x16x32_bf16(a[mf], bb[nf], acc[mf][nf], 0, 0, 0);
        }
    }
    int lgrp = lane >> 4;
    #pragma unroll
    for (int mf = 0; mf < 2; ++mf) {
        #pragma unroll
        for (int nf = 0; nf < 2; ++nf) {
            int col = n0 + wc * 32 + nf * 16 + lane15;
            int row0 = m0 + wr * 32 + mf * 16 + lgrp * 4;
            #pragma unroll
            for (int rr = 0; rr < 4; ++rr)
                out[(long)(row0 + rr) * DS_ + col] = acc[mf][nf][rr];
        }
    }
}

extern "C" void kernel_launch(void* const* d_in, const int* in_sizes, int n_in,
                              void* d_out, int out_size, void* d_ws, size_t ws_size,
                              hipStream_t stream) {
    const float* single = (const float*)d_in[0];
    const float* pw     = (const float*)d_in[1];
    const float* gamma  = (const float*)d_in[2];
    const float* beta   = (const float*)d_in[3];
    const float* wb     = (const float*)d_in[4];
    const float* abb    = (const float*)d_in[5];
    const float* wq     = (const float*)d_in[6];
    const float* wk     = (const float*)d_in[7];
    const float* wv     = (const float*)d_in[8];
    const float* wg     = (const float*)d_in[9];
    const float* wo     = (const float*)d_in[10];
    float* out = (float*)d_out;
    char* ws = (char*)d_ws;

    unsigned short* SP  = (unsigned short*)(ws);                 // 16 MB bias [b][h][i][j]
    unsigned short* Qb  = (unsigned short*)(ws + 16777216);      // 2 MB (pre-scaled 0.125)
    unsigned short* Kb  = (unsigned short*)(ws + 18874368);      // 2 MB
    unsigned short* Vt  = (unsigned short*)(ws + 20971520);      // 2 MB [b][h][dh][n]
    unsigned short* Xg  = (unsigned short*)(ws + 23068672);      // 2 MB
    unsigned short* Og  = (unsigned short*)(ws + 25165824);      // 2 MB
    unsigned short* Wt  = (unsigned short*)(ws + 27262976);      // 3 MB [4*1024][384]
    unsigned short* Wot = (unsigned short*)(ws + 30408704);      // 0.75 MB [384][1024]
    unsigned short* GhG = (unsigned short*)(ws + 31195136);      // 4 KB  [16][128] bf16
    float* SsG          = (float*)(ws + 31199232);               // 64 B
    float* TsG          = (float*)(ws + 31199296);               // 64 B

    k_transpose_all<<<dim3(32, 32, 6), 256, 0, stream>>>(wq, wk, wv, wg, wo,
                                                         gamma, beta, wb,
                                                         Wt, Wot, GhG, SsG, TsG);
    k_bias<<<8192, 256, 0, stream>>>(pw, abb, GhG, SsG, TsG, SP);
    k_proj<<<dim3(8, 32), 256, 0, stream>>>(single, Wt, Qb, Kb, Vt, Xg);
    k_flash<<<dim3(8, 32), 512, 0, stream>>>(Qb, Kb, Vt, SP, Xg, Og);
    k_out<<<dim3(16, 6), 256, 0, stream>>>(Og, Wot, out);
}